// Round 1
// baseline (402.423 us; speedup 1.0000x reference)
//
#include <hip/hip_runtime.h>
#include <stdint.h>

// Problem constants (fixed shapes from reference):
// x: [B=4][T=2048][D=1024] fp32, H=16 heads, hd=64.
#define B_   4
#define T_   2048
#define H_   16
#define HD_  64
#define D_   1024
#define QB   128              // query rows per block
#define KB   64               // key rows per KV step
#define NSTEP (T_ / KB)       // 32
#define L2E  1.44269504088896f

typedef __attribute__((ext_vector_type(4))) float    f32x4;
typedef __attribute__((ext_vector_type(8))) _Float16 f16x8;

__device__ __forceinline__ f32x4 mfma16(f16x8 a, f16x8 b, f32x4 c) {
  return __builtin_amdgcn_mfma_f32_16x16x32_f16(a, b, c, 0, 0, 0);
}

// ---------------- kernel 1: per-(b, d) column mean over T -------------------
__global__ __launch_bounds__(256)
void colmean_kernel(const float* __restrict__ x, float* __restrict__ mu) {
  const int b   = blockIdx.x >> 6;          // 0..3
  const int c0  = (blockIdx.x & 63) << 4;   // 64 chunks of 16 cols
  const int col = threadIdx.x & 15;
  const int rg  = threadIdx.x >> 4;         // 0..15, each sums 128 rows
  const float* p = x + ((size_t)(b * T_ + rg * 128)) * D_ + c0 + col;
  float s = 0.f;
  #pragma unroll 8
  for (int r = 0; r < 128; ++r) s += p[(size_t)r * D_];
  __shared__ float red[16][17];
  red[rg][col] = s;
  __syncthreads();
  if (rg == 0) {
    float t = 0.f;
    #pragma unroll
    for (int i = 0; i < 16; ++i) t += red[i][col];
    mu[b * D_ + c0 + col] = t * (1.f / (float)T_);
  }
}

// ---------------- kernel 2: flash attention per (b,h) -----------------------
// Q = K = centered x-head (f16), V = raw x-head (f16), fp32 accumulate.
// Block: 256 thr = 4 waves; each wave owns 32 query rows (2x 16-row MFMA tiles).
__global__ __launch_bounds__(256)
void attn_kernel(const float* __restrict__ x, const float* __restrict__ mu,
                 float* __restrict__ out) {
  // K: [key][d] row-major, 64 elem (128B) rows, XOR-swizzled (G4).
  // V: [d][key] (transposed), same swizzle.
  // P: per-wave per-qtile [q][key], same swizzle.
  __shared__ __align__(16) _Float16 Kt[64 * 64];
  __shared__ __align__(16) _Float16 Vt[64 * 64];
  __shared__ __align__(16) _Float16 Pl[4][2][16 * 64];

  const int tid  = threadIdx.x;
  const int lane = tid & 63;
  const int wv   = tid >> 6;      // wave 0..3
  const int j    = lane & 15;     // MFMA "16-lane" index
  const int g    = lane >> 4;     // MFMA lane group 0..3

  const int qb = blockIdx.x & 15; // 16 query tiles
  const int bh = blockIdx.x >> 4; // 64 (b,h) pairs
  const int b  = bh >> 4;
  const int h  = bh & 15;

  const float* xb  = x  + (size_t)b * T_ * D_;
  const float* muh = mu + b * D_ + h * HD_;

  // ---- Q fragments (held in registers for whole kernel) ----
  // A-frag layout: row = lane&15, k = (lane>>4)*8 + e  (8 contiguous d's)
  f16x8 qf[2][2];
  const int q0 = qb * QB + wv * 32;
  #pragma unroll
  for (int qt = 0; qt < 2; ++qt) {
    const float* qrow = xb + (size_t)(q0 + qt * 16 + j) * D_ + h * HD_;
    #pragma unroll
    for (int ks = 0; ks < 2; ++ks) {
      const int d0 = ks * 32 + g * 8;
      float4 a  = *(const float4*)(qrow + d0);
      float4 c  = *(const float4*)(qrow + d0 + 4);
      float4 m0 = *(const float4*)(muh + d0);
      float4 m1 = *(const float4*)(muh + d0 + 4);
      f16x8 f;
      f[0] = (_Float16)(a.x - m0.x); f[1] = (_Float16)(a.y - m0.y);
      f[2] = (_Float16)(a.z - m0.z); f[3] = (_Float16)(a.w - m0.w);
      f[4] = (_Float16)(c.x - m1.x); f[5] = (_Float16)(c.y - m1.y);
      f[6] = (_Float16)(c.z - m1.z); f[7] = (_Float16)(c.w - m1.w);
      qf[qt][ks] = f;
    }
  }

  // staging maps
  const int kd0 = (tid & 7) * 8;          // K: this thread's 8 d's (fixed)
  const float4 kmu0 = *(const float4*)(muh + kd0);
  const float4 kmu1 = *(const float4*)(muh + kd0 + 4);
  const int vd2 = (tid & 31) * 2;         // V: 2 d-rows per thread
  const int vkc = tid >> 5;               // V: key chunk 0..7

  f32x4 acc[2][4];                        // [qtile][d-tile] output accum
  float mrun[2][4], lrun[2][4];           // online-softmax row stats
  #pragma unroll
  for (int qt = 0; qt < 2; ++qt) {
    #pragma unroll
    for (int n = 0; n < 4; ++n) acc[qt][n] = f32x4{0.f, 0.f, 0.f, 0.f};
    #pragma unroll
    for (int r = 0; r < 4; ++r) { mrun[qt][r] = -1e30f; lrun[qt][r] = 0.f; }
  }

  const int swj = (j & 7) << 3;           // element-unit swizzle for read rows

  for (int step = 0; step < NSTEP; ++step) {
    const size_t krow0 = (size_t)(step * KB) * D_ + h * HD_;
    __syncthreads();  // previous step's LDS reads done (WAR)

    // ---- stage K: centered f16, [key][d], swizzled ----
    #pragma unroll
    for (int cc = 0; cc < 2; ++cc) {
      const int kk = (tid >> 3) + cc * 32;
      const float* src = xb + krow0 + (size_t)kk * D_ + kd0;
      float4 a = *(const float4*)src;
      float4 c = *(const float4*)(src + 4);
      f16x8 f;
      f[0] = (_Float16)(a.x - kmu0.x); f[1] = (_Float16)(a.y - kmu0.y);
      f[2] = (_Float16)(a.z - kmu0.z); f[3] = (_Float16)(a.w - kmu0.w);
      f[4] = (_Float16)(c.x - kmu1.x); f[5] = (_Float16)(c.y - kmu1.y);
      f[6] = (_Float16)(c.z - kmu1.z); f[7] = (_Float16)(c.w - kmu1.w);
      *(f16x8*)&Kt[kk * 64 + (kd0 ^ ((kk & 7) << 3))] = f;
    }
    // ---- stage V transposed: raw f16, [d][key], swizzled ----
    {
      float2 t[8];
      #pragma unroll
      for (int e = 0; e < 8; ++e)
        t[e] = *(const float2*)(xb + krow0 + (size_t)(vkc * 8 + e) * D_ + vd2);
      f16x8 f0, f1;
      #pragma unroll
      for (int e = 0; e < 8; ++e) {
        f0[e] = (_Float16)t[e].x;
        f1[e] = (_Float16)t[e].y;
      }
      *(f16x8*)&Vt[(vd2    ) * 64 + ((vkc * 8) ^ (((vd2    ) & 7) << 3))] = f0;
      *(f16x8*)&Vt[(vd2 + 1) * 64 + ((vkc * 8) ^ (((vd2 + 1) & 7) << 3))] = f1;
    }
    __syncthreads();  // staging visible

    // ---- S = Q · K^T  (16 MFMAs: 4 key-tiles x 2 k-slices x 2 qtiles) ----
    f32x4 s[2][4];
    #pragma unroll
    for (int n = 0; n < 4; ++n) {
      const int rb = (n * 16 + j) * 64;   // B-frag: col=lane&15 -> key row
      f16x8 kb0 = *(const f16x8*)&Kt[rb + (((     g * 8)) ^ swj)];
      f16x8 kb1 = *(const f16x8*)&Kt[rb + (((32 + g * 8)) ^ swj)];
      #pragma unroll
      for (int qt = 0; qt < 2; ++qt) {
        f32x4 z = f32x4{0.f, 0.f, 0.f, 0.f};
        z = mfma16(qf[qt][0], kb0, z);
        s[qt][n] = mfma16(qf[qt][1], kb1, z);
      }
    }

    // ---- online softmax + P write (C layout: col=lane&15, row=g*4+r) ----
    #pragma unroll
    for (int qt = 0; qt < 2; ++qt) {
      float al[4];
      #pragma unroll
      for (int r = 0; r < 4; ++r) {
        float v = fmaxf(fmaxf(s[qt][0][r], s[qt][1][r]),
                        fmaxf(s[qt][2][r], s[qt][3][r]));
        v = fmaxf(v, __shfl_xor(v, 1, 16));
        v = fmaxf(v, __shfl_xor(v, 2, 16));
        v = fmaxf(v, __shfl_xor(v, 4, 16));
        v = fmaxf(v, __shfl_xor(v, 8, 16));
        const float mn = fmaxf(mrun[qt][r], v);
        al[r] = exp2f((mrun[qt][r] - mn) * L2E);
        mrun[qt][r] = mn;
        float p0 = exp2f((s[qt][0][r] - mn) * L2E);
        float p1 = exp2f((s[qt][1][r] - mn) * L2E);
        float p2 = exp2f((s[qt][2][r] - mn) * L2E);
        float p3 = exp2f((s[qt][3][r] - mn) * L2E);
        float rs = (p0 + p1) + (p2 + p3);
        rs += __shfl_xor(rs, 1, 16);
        rs += __shfl_xor(rs, 2, 16);
        rs += __shfl_xor(rs, 4, 16);
        rs += __shfl_xor(rs, 8, 16);
        lrun[qt][r] = lrun[qt][r] * al[r] + rs;
        const int q   = g * 4 + r;
        const int qsw = (q & 7) << 3;
        _Float16* prow = &Pl[wv][qt][q * 64];
        prow[(     j) ^ qsw] = (_Float16)p0;
        prow[(16 + j) ^ qsw] = (_Float16)p1;
        prow[(32 + j) ^ qsw] = (_Float16)p2;
        prow[(48 + j) ^ qsw] = (_Float16)p3;
      }
      #pragma unroll
      for (int n = 0; n < 4; ++n) {
        acc[qt][n][0] *= al[0]; acc[qt][n][1] *= al[1];
        acc[qt][n][2] *= al[2]; acc[qt][n][3] *= al[3];
      }
    }

    // P write (cross-lane) -> P read: same wave, DS pipe is in-order, but
    // force compile-time ordering + drain (guide rule #18 territory).
    asm volatile("s_waitcnt lgkmcnt(0)" ::: "memory");

    // ---- O += P · V  (16 MFMAs) ----
    f16x8 pa[2][2];
    #pragma unroll
    for (int qt = 0; qt < 2; ++qt) {
      const _Float16* Pw = &Pl[wv][qt][0];
      pa[qt][0] = *(const f16x8*)&Pw[j * 64 + (((     g * 8)) ^ swj)];
      pa[qt][1] = *(const f16x8*)&Pw[j * 64 + (((32 + g * 8)) ^ swj)];
    }
    #pragma unroll
    for (int n = 0; n < 4; ++n) {
      const int rb = (n * 16 + j) * 64;   // B-frag: col=lane&15 -> d row of Vt
      f16x8 v0 = *(const f16x8*)&Vt[rb + (((     g * 8)) ^ swj)];
      f16x8 v1 = *(const f16x8*)&Vt[rb + (((32 + g * 8)) ^ swj)];
      #pragma unroll
      for (int qt = 0; qt < 2; ++qt) {
        acc[qt][n] = mfma16(pa[qt][0], v0, acc[qt][n]);
        acc[qt][n] = mfma16(pa[qt][1], v1, acc[qt][n]);
      }
    }
  }

  // ---- epilogue: out = acc / l ----
  #pragma unroll
  for (int qt = 0; qt < 2; ++qt) {
    float inv[4];
    #pragma unroll
    for (int r = 0; r < 4; ++r) inv[r] = 1.0f / lrun[qt][r];
    #pragma unroll
    for (int n = 0; n < 4; ++n) {
      #pragma unroll
      for (int r = 0; r < 4; ++r) {
        const int q = q0 + qt * 16 + g * 4 + r;
        out[(size_t)(b * T_ + q) * D_ + h * HD_ + n * 16 + j] =
            acc[qt][n][r] * inv[r];
      }
    }
  }
}

extern "C" void kernel_launch(void* const* d_in, const int* in_sizes, int n_in,
                              void* d_out, int out_size, void* d_ws, size_t ws_size,
                              hipStream_t stream) {
  (void)in_sizes; (void)n_in; (void)out_size; (void)ws_size;
  const float* x  = (const float*)d_in[0];
  float* outp     = (float*)d_out;
  float* mu       = (float*)d_ws;          // B_*D_ floats = 16 KB, rewritten fully each call

  hipLaunchKernelGGL(colmean_kernel, dim3(B_ * 64), dim3(256), 0, stream, x, mu);
  hipLaunchKernelGGL(attn_kernel, dim3((T_ / QB) * B_ * H_), dim3(256), 0, stream,
                     x, mu, outp);
}

// Round 2
// 188.194 us; speedup vs baseline: 2.1383x; 2.1383x over previous
//
#include <hip/hip_runtime.h>
#include <stdint.h>

// x: [B=4][T=2048][D=1024] fp32, H=16 heads, hd=64.
#define B_   4
#define T_   2048
#define H_   16
#define HD_  64
#define D_   1024
#define QB   128              // query rows per block
#define KB   64               // key rows per KV step
#define NSTEP (T_ / KB)       // 32
#define L2E  1.44269504088896f

typedef __attribute__((ext_vector_type(4))) float    f32x4;
typedef __attribute__((ext_vector_type(8))) _Float16 f16x8;
typedef __attribute__((ext_vector_type(4))) _Float16 f16x4;

__device__ __forceinline__ f32x4 mfma16(f16x8 a, f16x8 b, f32x4 c) {
  return __builtin_amdgcn_mfma_f32_16x16x32_f16(a, b, c, 0, 0, 0);
}

// async global->LDS, 16B per lane; LDS dest = wave-uniform base + lane*16
__device__ __forceinline__ void gld16(const void* g, void* l) {
  __builtin_amdgcn_global_load_lds(
      (const __attribute__((address_space(1))) uint32_t*)g,
      (__attribute__((address_space(3))) uint32_t*)l, 16, 0, 0);
}

// ---------------- kernel 1: per-(b,d) column mean over T --------------------
__global__ __launch_bounds__(256)
void colmean_kernel(const float* __restrict__ x, float* __restrict__ mu) {
  const int b   = blockIdx.x >> 6;
  const int c0  = (blockIdx.x & 63) << 4;
  const int col = threadIdx.x & 15;
  const int rg  = threadIdx.x >> 4;
  const float* p = x + ((size_t)(b * T_ + rg * 128)) * D_ + c0 + col;
  float s = 0.f;
  #pragma unroll 8
  for (int r = 0; r < 128; ++r) s += p[(size_t)r * D_];
  __shared__ float red[16][17];
  red[rg][col] = s;
  __syncthreads();
  if (rg == 0) {
    float t = 0.f;
    #pragma unroll
    for (int i = 0; i < 16; ++i) t += red[i][col];
    mu[b * D_ + c0 + col] = t * (1.f / (float)T_);
  }
}

// ---------------- kernel 2: centered f16 + transposed copy ------------------
// C16 [b][t][d] = (x - mu) f16;  CT16 [(b*16+h)][d(0..63)][t] = same, transposed.
__global__ __launch_bounds__(256)
void cvt_kernel(const float* __restrict__ x, const float* __restrict__ mu,
                _Float16* __restrict__ c16, _Float16* __restrict__ ct16) {
  const int blk = blockIdx.x;          // 512 blocks
  const int hq  = blk & 3;
  const int tt  = (blk >> 2) & 31;
  const int b   = blk >> 7;
  const int wv  = threadIdx.x >> 6;
  const int l   = threadIdx.x & 63;
  const int h   = hq * 4 + wv;
  const int t   = tt * 64 + l;
  const float* xr  = x  + ((size_t)(b * T_ + t)) * D_ + h * HD_;
  const float* mur = mu + b * D_ + h * HD_;
  _Float16* crow = c16 + ((size_t)(b * T_ + t)) * D_ + h * HD_;
  _Float16* ct   = ct16 + (((size_t)(b * H_ + h)) * HD_) * T_ + t;
  #pragma unroll
  for (int c = 0; c < 4; ++c) {
    float4 f[4];
    #pragma unroll
    for (int u = 0; u < 4; ++u) f[u] = *(const float4*)(xr + c * 16 + u * 4);
    _Float16 cf[16];
    #pragma unroll
    for (int u = 0; u < 4; ++u) {
      cf[u*4+0] = (_Float16)(f[u].x - mur[c*16 + u*4 + 0]);
      cf[u*4+1] = (_Float16)(f[u].y - mur[c*16 + u*4 + 1]);
      cf[u*4+2] = (_Float16)(f[u].z - mur[c*16 + u*4 + 2]);
      cf[u*4+3] = (_Float16)(f[u].w - mur[c*16 + u*4 + 3]);
    }
    *(f16x8*)(crow + c * 16)     = *(f16x8*)&cf[0];
    *(f16x8*)(crow + c * 16 + 8) = *(f16x8*)&cf[8];
    #pragma unroll
    for (int d = 0; d < 16; ++d) ct[(size_t)(c * 16 + d) * T_] = cf[d];  // coalesced across lanes (t)
  }
}

// ---------------- kernel 3: flash attention, swapped-QK^T -------------------
__global__ __launch_bounds__(256, 3)
void attn2_kernel(const _Float16* __restrict__ c16,
                  const _Float16* __restrict__ ct16,
                  const float* __restrict__ mu,
                  float* __restrict__ out) {
  // K/V tiles: 64 rows x 64 f16 (128B), double-buffered, XOR-swizzled content
  // (swizzle applied via pre-swizzled GLOBAL source; LDS dest linear).
  __shared__ __align__(16) _Float16 Kb[2][64 * 64];
  __shared__ __align__(16) _Float16 Vb[2][64 * 64];
  __shared__ __align__(16) _Float16 Pl[4][2][16 * 64];

  const int tid  = threadIdx.x;
  const int lane = tid & 63;
  const int wv   = tid >> 6;
  const int j    = lane & 15;
  const int g    = lane >> 4;

  // XCD-aware swizzle: grid 1024 = 8 XCDs x 128; the 16 q-tile blocks of one
  // (b,h) land on one XCD -> K/V stream L2-resident.
  const int bid = blockIdx.x;
  const int wid = (bid & 7) * 128 + (bid >> 3);
  const int qb  = wid & 15;
  const int bh  = wid >> 4;
  const int b   = bh >> 4;
  const int h   = bh & 15;

  // ---- Q fragments (registers, whole kernel). B-frag: col=lane&15 (=q),
  // k=(lane>>4)*8+e (=d). Same per-lane data as an A-frag -> plain row loads.
  f16x8 qf[2][2];
  const int q0 = qb * QB + wv * 32;
  #pragma unroll
  for (int qt = 0; qt < 2; ++qt) {
    const _Float16* qrow = c16 + ((size_t)(b * T_ + q0 + qt * 16 + j)) * D_ + h * HD_;
    #pragma unroll
    for (int ks = 0; ks < 2; ++ks)
      qf[qt][ks] = *(const f16x8*)(qrow + ks * 32 + g * 8);
  }

  // staging source addresses (pre-swizzled granule: c' = c ^ rowlocal&7)
  const int srow = wv * 16 + (lane >> 3);        // local row for instr i=0
  const int cp   = (lane & 7) ^ (lane >> 3);     // swizzled 16B granule
  const char* ksrc = (const char*)c16 +
      (((size_t)(b * T_) + srow) * D_ + h * HD_) * 2 + cp * 16;
  const char* vsrc = (const char*)ct16 +
      (((size_t)(bh * HD_) + srow) * T_) * 2 + cp * 16;

  f32x4 acc[2][4];
  float mrun[2], lrun[2];
  #pragma unroll
  for (int qt = 0; qt < 2; ++qt) {
    #pragma unroll
    for (int n = 0; n < 4; ++n) acc[qt][n] = f32x4{0.f, 0.f, 0.f, 0.f};
    mrun[qt] = -1e30f; lrun[qt] = 0.f;
  }

  const int swj = (j & 7) << 3;

  // prologue: stage tile 0
  {
    gld16(ksrc,                      &Kb[0][(wv * 16    ) * 64]);
    gld16(ksrc + 8 * D_ * 2,         &Kb[0][(wv * 16 + 8) * 64]);
    gld16(vsrc,                      &Vb[0][(wv * 16    ) * 64]);
    gld16(vsrc + 8 * T_ * 2,         &Vb[0][(wv * 16 + 8) * 64]);
  }
  __syncthreads();

  int buf = 0;
  for (int step = 0; step < NSTEP; ++step) {
    // ---- issue next-tile staging (overlaps with compute below) ----
    if (step + 1 < NSTEP) {
      const char* k1 = ksrc + (size_t)(step + 1) * (KB * D_ * 2);
      const char* v1 = vsrc + (size_t)(step + 1) * (KB * 2);
      gld16(k1,              &Kb[buf ^ 1][(wv * 16    ) * 64]);
      gld16(k1 + 8 * D_ * 2, &Kb[buf ^ 1][(wv * 16 + 8) * 64]);
      gld16(v1,              &Vb[buf ^ 1][(wv * 16    ) * 64]);
      gld16(v1 + 8 * T_ * 2, &Vb[buf ^ 1][(wv * 16 + 8) * 64]);
    }

    // ---- S^T = K · Q^T (swapped): C[row=key][col=q] ----
    f32x4 s[2][4];
    #pragma unroll
    for (int n = 0; n < 4; ++n) {
      const int rb = (n * 16 + j) * 64;   // A-frag: row=lane&15 -> key n*16+j
      f16x8 kb0 = *(const f16x8*)&Kb[buf][rb + (((     g * 8)) ^ swj)];
      f16x8 kb1 = *(const f16x8*)&Kb[buf][rb + (((32 + g * 8)) ^ swj)];
      #pragma unroll
      for (int qt = 0; qt < 2; ++qt) {
        f32x4 z = f32x4{0.f, 0.f, 0.f, 0.f};
        z = mfma16(kb0, qf[qt][0], z);
        s[qt][n] = mfma16(kb1, qf[qt][1], z);
      }
    }

    // ---- softmax: lane owns q=j; keys 16n+4g+r in-register ----
    #pragma unroll
    for (int qt = 0; qt < 2; ++qt) {
      float pm = s[qt][0][0];
      #pragma unroll
      for (int n = 0; n < 4; ++n)
        #pragma unroll
        for (int r = 0; r < 4; ++r) pm = fmaxf(pm, s[qt][n][r]);
      pm = fmaxf(pm, __shfl_xor(pm, 16));
      pm = fmaxf(pm, __shfl_xor(pm, 32));
      const float mn = fmaxf(mrun[qt], pm);
      const float al = exp2f((mrun[qt] - mn) * L2E);
      mrun[qt] = mn;
      float p[4][4];
      float rs = 0.f;
      #pragma unroll
      for (int n = 0; n < 4; ++n) {
        p[n][0] = exp2f((s[qt][n][0] - mn) * L2E);
        p[n][1] = exp2f((s[qt][n][1] - mn) * L2E);
        p[n][2] = exp2f((s[qt][n][2] - mn) * L2E);
        p[n][3] = exp2f((s[qt][n][3] - mn) * L2E);
        rs += (p[n][0] + p[n][1]) + (p[n][2] + p[n][3]);
      }
      rs += __shfl_xor(rs, 16);
      rs += __shfl_xor(rs, 32);
      lrun[qt] = lrun[qt] * al + rs;
      // P write: row q=j, keys 16n+4g..+3, swizzled by this row's swj
      #pragma unroll
      for (int n = 0; n < 4; ++n) {
        f16x4 w;
        w[0] = (_Float16)p[n][0]; w[1] = (_Float16)p[n][1];
        w[2] = (_Float16)p[n][2]; w[3] = (_Float16)p[n][3];
        *(f16x4*)&Pl[wv][qt][j * 64 + ((16 * n + 4 * g) ^ swj)] = w;
      }
      // rescale acc rows (row q' = 4g+r) with alpha broadcast from lane j'=4g+r
      float alr[4];
      #pragma unroll
      for (int r = 0; r < 4; ++r)
        alr[r] = __shfl(al, (lane & 48) | (4 * g + r));
      #pragma unroll
      for (int n = 0; n < 4; ++n) {
        acc[qt][n][0] *= alr[0]; acc[qt][n][1] *= alr[1];
        acc[qt][n][2] *= alr[2]; acc[qt][n][3] *= alr[3];
      }
    }

    // ---- O += P · V  (A-frag of P: row=q=j, k=key; same-wave write->read) ----
    f16x8 pa[2][2];
    #pragma unroll
    for (int qt = 0; qt < 2; ++qt) {
      const _Float16* Pw = &Pl[wv][qt][0];
      pa[qt][0] = *(const f16x8*)&Pw[j * 64 + (((     g * 8)) ^ swj)];
      pa[qt][1] = *(const f16x8*)&Pw[j * 64 + (((32 + g * 8)) ^ swj)];
    }
    #pragma unroll
    for (int n = 0; n < 4; ++n) {
      const int rb = (n * 16 + j) * 64;   // B-frag: col=lane&15 -> d row of Vb
      f16x8 v0 = *(const f16x8*)&Vb[buf][rb + (((     g * 8)) ^ swj)];
      f16x8 v1 = *(const f16x8*)&Vb[buf][rb + (((32 + g * 8)) ^ swj)];
      #pragma unroll
      for (int qt = 0; qt < 2; ++qt) {
        acc[qt][n] = mfma16(pa[qt][0], v0, acc[qt][n]);
        acc[qt][n] = mfma16(pa[qt][1], v1, acc[qt][n]);
      }
    }

    __syncthreads();   // drains this wave's gld16 (vmcnt0) + all waves' reads
    buf ^= 1;
  }

  // ---- epilogue: out = acc / l + mu ----
  float mval[4];
  #pragma unroll
  for (int n = 0; n < 4; ++n) mval[n] = mu[b * D_ + h * HD_ + n * 16 + j];
  #pragma unroll
  for (int qt = 0; qt < 2; ++qt) {
    const float linv = 1.0f / lrun[qt];
    float lr[4];
    #pragma unroll
    for (int r = 0; r < 4; ++r)
      lr[r] = __shfl(linv, (lane & 48) | (4 * g + r));
    #pragma unroll
    for (int n = 0; n < 4; ++n) {
      #pragma unroll
      for (int r = 0; r < 4; ++r) {
        const int q = q0 + qt * 16 + 4 * g + r;
        out[(size_t)(b * T_ + q) * D_ + h * HD_ + n * 16 + j] =
            acc[qt][n][r] * lr[r] + mval[n];
      }
    }
  }
}

// ---------------- fallback: verified round-1 kernel (small ws) --------------
__global__ __launch_bounds__(256)
void attn_fb_kernel(const float* __restrict__ x, const float* __restrict__ mu,
                    float* __restrict__ out) {
  __shared__ __align__(16) _Float16 Kt[64 * 64];
  __shared__ __align__(16) _Float16 Vt[64 * 64];
  __shared__ __align__(16) _Float16 Pl[4][2][16 * 64];

  const int tid  = threadIdx.x;
  const int lane = tid & 63;
  const int wv   = tid >> 6;
  const int j    = lane & 15;
  const int g    = lane >> 4;

  const int qb = blockIdx.x & 15;
  const int bh = blockIdx.x >> 4;
  const int b  = bh >> 4;
  const int h  = bh & 15;

  const float* xb  = x  + (size_t)b * T_ * D_;
  const float* muh = mu + b * D_ + h * HD_;

  f16x8 qf[2][2];
  const int q0 = qb * QB + wv * 32;
  #pragma unroll
  for (int qt = 0; qt < 2; ++qt) {
    const float* qrow = xb + (size_t)(q0 + qt * 16 + j) * D_ + h * HD_;
    #pragma unroll
    for (int ks = 0; ks < 2; ++ks) {
      const int d0 = ks * 32 + g * 8;
      float4 a  = *(const float4*)(qrow + d0);
      float4 c  = *(const float4*)(qrow + d0 + 4);
      float4 m0 = *(const float4*)(muh + d0);
      float4 m1 = *(const float4*)(muh + d0 + 4);
      f16x8 f;
      f[0] = (_Float16)(a.x - m0.x); f[1] = (_Float16)(a.y - m0.y);
      f[2] = (_Float16)(a.z - m0.z); f[3] = (_Float16)(a.w - m0.w);
      f[4] = (_Float16)(c.x - m1.x); f[5] = (_Float16)(c.y - m1.y);
      f[6] = (_Float16)(c.z - m1.z); f[7] = (_Float16)(c.w - m1.w);
      qf[qt][ks] = f;
    }
  }

  const int kd0 = (tid & 7) * 8;
  const float4 kmu0 = *(const float4*)(muh + kd0);
  const float4 kmu1 = *(const float4*)(muh + kd0 + 4);
  const int vd2 = (tid & 31) * 2;
  const int vkc = tid >> 5;

  f32x4 acc[2][4];
  float mrun[2][4], lrun[2][4];
  #pragma unroll
  for (int qt = 0; qt < 2; ++qt) {
    #pragma unroll
    for (int n = 0; n < 4; ++n) acc[qt][n] = f32x4{0.f, 0.f, 0.f, 0.f};
    #pragma unroll
    for (int r = 0; r < 4; ++r) { mrun[qt][r] = -1e30f; lrun[qt][r] = 0.f; }
  }

  const int swj = (j & 7) << 3;

  for (int step = 0; step < NSTEP; ++step) {
    const size_t krow0 = (size_t)(step * KB) * D_ + h * HD_;
    __syncthreads();

    #pragma unroll
    for (int cc = 0; cc < 2; ++cc) {
      const int kk = (tid >> 3) + cc * 32;
      const float* src = xb + krow0 + (size_t)kk * D_ + kd0;
      float4 a = *(const float4*)src;
      float4 c = *(const float4*)(src + 4);
      f16x8 f;
      f[0] = (_Float16)(a.x - kmu0.x); f[1] = (_Float16)(a.y - kmu0.y);
      f[2] = (_Float16)(a.z - kmu0.z); f[3] = (_Float16)(a.w - kmu0.w);
      f[4] = (_Float16)(c.x - kmu1.x); f[5] = (_Float16)(c.y - kmu1.y);
      f[6] = (_Float16)(c.z - kmu1.z); f[7] = (_Float16)(c.w - kmu1.w);
      *(f16x8*)&Kt[kk * 64 + (kd0 ^ ((kk & 7) << 3))] = f;
    }
    {
      float2 t[8];
      #pragma unroll
      for (int e = 0; e < 8; ++e)
        t[e] = *(const float2*)(xb + krow0 + (size_t)(vkc * 8 + e) * D_ + vd2);
      f16x8 f0, f1;
      #pragma unroll
      for (int e = 0; e < 8; ++e) { f0[e] = (_Float16)t[e].x; f1[e] = (_Float16)t[e].y; }
      *(f16x8*)&Vt[(vd2    ) * 64 + ((vkc * 8) ^ (((vd2    ) & 7) << 3))] = f0;
      *(f16x8*)&Vt[(vd2 + 1) * 64 + ((vkc * 8) ^ (((vd2 + 1) & 7) << 3))] = f1;
    }
    __syncthreads();

    f32x4 s[2][4];
    #pragma unroll
    for (int n = 0; n < 4; ++n) {
      const int rb = (n * 16 + j) * 64;
      f16x8 kb0 = *(const f16x8*)&Kt[rb + (((     g * 8)) ^ swj)];
      f16x8 kb1 = *(const f16x8*)&Kt[rb + (((32 + g * 8)) ^ swj)];
      #pragma unroll
      for (int qt = 0; qt < 2; ++qt) {
        f32x4 z = f32x4{0.f, 0.f, 0.f, 0.f};
        z = mfma16(qf[qt][0], kb0, z);
        s[qt][n] = mfma16(qf[qt][1], kb1, z);
      }
    }

    #pragma unroll
    for (int qt = 0; qt < 2; ++qt) {
      float al[4];
      #pragma unroll
      for (int r = 0; r < 4; ++r) {
        float v = fmaxf(fmaxf(s[qt][0][r], s[qt][1][r]),
                        fmaxf(s[qt][2][r], s[qt][3][r]));
        v = fmaxf(v, __shfl_xor(v, 1, 16));
        v = fmaxf(v, __shfl_xor(v, 2, 16));
        v = fmaxf(v, __shfl_xor(v, 4, 16));
        v = fmaxf(v, __shfl_xor(v, 8, 16));
        const float mn = fmaxf(mrun[qt][r], v);
        al[r] = exp2f((mrun[qt][r] - mn) * L2E);
        mrun[qt][r] = mn;
        float p0 = exp2f((s[qt][0][r] - mn) * L2E);
        float p1 = exp2f((s[qt][1][r] - mn) * L2E);
        float p2 = exp2f((s[qt][2][r] - mn) * L2E);
        float p3 = exp2f((s[qt][3][r] - mn) * L2E);
        float rs = (p0 + p1) + (p2 + p3);
        rs += __shfl_xor(rs, 1, 16);
        rs += __shfl_xor(rs, 2, 16);
        rs += __shfl_xor(rs, 4, 16);
        rs += __shfl_xor(rs, 8, 16);
        lrun[qt][r] = lrun[qt][r] * al[r] + rs;
        const int q   = g * 4 + r;
        const int qsw = (q & 7) << 3;
        _Float16* prow = &Pl[wv][qt][q * 64];
        prow[(     j) ^ qsw] = (_Float16)p0;
        prow[(16 + j) ^ qsw] = (_Float16)p1;
        prow[(32 + j) ^ qsw] = (_Float16)p2;
        prow[(48 + j) ^ qsw] = (_Float16)p3;
      }
      #pragma unroll
      for (int n = 0; n < 4; ++n) {
        acc[qt][n][0] *= al[0]; acc[qt][n][1] *= al[1];
        acc[qt][n][2] *= al[2]; acc[qt][n][3] *= al[3];
      }
    }

    asm volatile("s_waitcnt lgkmcnt(0)" ::: "memory");

    f16x8 pa[2][2];
    #pragma unroll
    for (int qt = 0; qt < 2; ++qt) {
      const _Float16* Pw = &Pl[wv][qt][0];
      pa[qt][0] = *(const f16x8*)&Pw[j * 64 + (((     g * 8)) ^ swj)];
      pa[qt][1] = *(const f16x8*)&Pw[j * 64 + (((32 + g * 8)) ^ swj)];
    }
    #pragma unroll
    for (int n = 0; n < 4; ++n) {
      const int rb = (n * 16 + j) * 64;
      f16x8 v0 = *(const f16x8*)&Vt[rb + (((     g * 8)) ^ swj)];
      f16x8 v1 = *(const f16x8*)&Vt[rb + (((32 + g * 8)) ^ swj)];
      #pragma unroll
      for (int qt = 0; qt < 2; ++qt) {
        acc[qt][n] = mfma16(pa[qt][0], v0, acc[qt][n]);
        acc[qt][n] = mfma16(pa[qt][1], v1, acc[qt][n]);
      }
    }
  }

  #pragma unroll
  for (int qt = 0; qt < 2; ++qt) {
    float inv[4];
    #pragma unroll
    for (int r = 0; r < 4; ++r) inv[r] = 1.0f / lrun[qt][r];
    #pragma unroll
    for (int n = 0; n < 4; ++n) {
      #pragma unroll
      for (int r = 0; r < 4; ++r) {
        const int q = q0 + qt * 16 + g * 4 + r;
        out[(size_t)(b * T_ + q) * D_ + h * HD_ + n * 16 + j] =
            acc[qt][n][r] * inv[r];
      }
    }
  }
}

extern "C" void kernel_launch(void* const* d_in, const int* in_sizes, int n_in,
                              void* d_out, int out_size, void* d_ws, size_t ws_size,
                              hipStream_t stream) {
  (void)in_sizes; (void)n_in; (void)out_size;
  const float* x  = (const float*)d_in[0];
  float* outp     = (float*)d_out;

  const size_t MU_BYTES  = (size_t)B_ * D_ * sizeof(float);     // 16 KB
  const size_t C16_BYTES = (size_t)B_ * T_ * D_ * 2;            // 16 MB

  float* mu = (float*)d_ws;
  hipLaunchKernelGGL(colmean_kernel, dim3(B_ * 64), dim3(256), 0, stream, x, mu);

  if (ws_size >= MU_BYTES + 2 * C16_BYTES) {
    _Float16* c16  = (_Float16*)((char*)d_ws + MU_BYTES);
    _Float16* ct16 = (_Float16*)((char*)d_ws + MU_BYTES + C16_BYTES);
    hipLaunchKernelGGL(cvt_kernel, dim3(512), dim3(256), 0, stream, x, mu, c16, ct16);
    hipLaunchKernelGGL(attn2_kernel, dim3((T_ / QB) * B_ * H_), dim3(256), 0, stream,
                       c16, ct16, mu, outp);
  } else {
    hipLaunchKernelGGL(attn_fb_kernel, dim3((T_ / QB) * B_ * H_), dim3(256), 0, stream,
                       x, mu, outp);
  }
}

// Round 3
// 159.059 us; speedup vs baseline: 2.5300x; 1.1832x over previous
//
#include <hip/hip_runtime.h>
#include <stdint.h>

// x: [B=4][T=2048][D=1024] fp32, H=16 heads, hd=64.
#define B_   4
#define T_   2048
#define H_   16
#define HD_  64
#define D_   1024
#define QB   128              // query rows per block (4 waves x 32)
#define KB   64               // key rows per KV step
#define NSTEP (T_ / KB)       // 32
#define L2E  1.44269504088896f
#define THR  8.0f             // defer-max threshold (P <= e^8 < f16 max)

typedef __attribute__((ext_vector_type(4)))  float    f32x4;
typedef __attribute__((ext_vector_type(16))) float    f32x16;
typedef __attribute__((ext_vector_type(8)))  _Float16 f16x8;
typedef __attribute__((ext_vector_type(4)))  _Float16 f16x4;

__device__ __forceinline__ f32x4 mfma16(f16x8 a, f16x8 b, f32x4 c) {
  return __builtin_amdgcn_mfma_f32_16x16x32_f16(a, b, c, 0, 0, 0);
}
__device__ __forceinline__ f32x16 mfma32(f16x8 a, f16x8 b, f32x16 c) {
  return __builtin_amdgcn_mfma_f32_32x32x16_f16(a, b, c, 0, 0, 0);
}
__device__ __forceinline__ f32x16 zero16() {
  f32x16 z;
  #pragma unroll
  for (int i = 0; i < 16; ++i) z[i] = 0.f;
  return z;
}
__device__ __forceinline__ uint32_t pkrtz(float a, float b) {
  auto r = __builtin_amdgcn_cvt_pkrtz(a, b);   // packed f16x2, RTZ
  return __builtin_bit_cast(uint32_t, r);
}
// v_permlane32_swap_b32 d, s: d's upper 32 lanes <-> s's lower 32 lanes.
__device__ __forceinline__ void pl32swap(uint32_t& a, uint32_t& b) {
  asm volatile("v_permlane32_swap_b32 %0, %1" : "+v"(a), "+v"(b));
}
__device__ __forceinline__ f16x8 mk_frag(uint32_t u0, uint32_t u1,
                                         uint32_t u2, uint32_t u3) {
  union { uint32_t u[4]; f16x8 v; } x;
  x.u[0] = u0; x.u[1] = u1; x.u[2] = u2; x.u[3] = u3;
  return x.v;
}
// async global->LDS, 16B/lane; LDS dest = wave-uniform base + lane*16
__device__ __forceinline__ void gld16(const void* g, void* l) {
  __builtin_amdgcn_global_load_lds(
      (const __attribute__((address_space(1))) uint32_t*)g,
      (__attribute__((address_space(3))) uint32_t*)l, 16, 0, 0);
}

// ---------------- kernel 1: per-(b,d) column mean over T --------------------
__global__ __launch_bounds__(256)
void colmean_kernel(const float* __restrict__ x, float* __restrict__ mu) {
  const int b   = blockIdx.x >> 6;
  const int c0  = (blockIdx.x & 63) << 4;
  const int col = threadIdx.x & 15;
  const int rg  = threadIdx.x >> 4;
  const float* p = x + ((size_t)(b * T_ + rg * 128)) * D_ + c0 + col;
  float s = 0.f;
  #pragma unroll 8
  for (int r = 0; r < 128; ++r) s += p[(size_t)r * D_];
  __shared__ float red[16][17];
  red[rg][col] = s;
  __syncthreads();
  if (rg == 0) {
    float t = 0.f;
    #pragma unroll
    for (int i = 0; i < 16; ++i) t += red[i][col];
    mu[b * D_ + c0 + col] = t * (1.f / (float)T_);
  }
}

// ---------------- kernel 2: centered f16 + transposed copy ------------------
// C16 [b][t][d] = (x-mu) f16;  CT16 [(b*16+h)][d(0..63)][t] = same, transposed.
__global__ __launch_bounds__(256)
void cvt_kernel(const float* __restrict__ x, const float* __restrict__ mu,
                _Float16* __restrict__ c16, _Float16* __restrict__ ct16) {
  const int blk = blockIdx.x;          // 512 blocks
  const int hq  = blk & 3;
  const int tt  = (blk >> 2) & 31;
  const int b   = blk >> 7;
  const int wv  = threadIdx.x >> 6;
  const int l   = threadIdx.x & 63;
  const int h   = hq * 4 + wv;
  const int t   = tt * 64 + l;
  const float* xr  = x  + ((size_t)(b * T_ + t)) * D_ + h * HD_;
  const float* mur = mu + b * D_ + h * HD_;
  _Float16* crow = c16 + ((size_t)(b * T_ + t)) * D_ + h * HD_;
  _Float16* ct   = ct16 + (((size_t)(b * H_ + h)) * HD_) * T_ + t;
  #pragma unroll
  for (int c = 0; c < 4; ++c) {
    float4 f[4];
    #pragma unroll
    for (int u = 0; u < 4; ++u) f[u] = *(const float4*)(xr + c * 16 + u * 4);
    _Float16 cf[16];
    #pragma unroll
    for (int u = 0; u < 4; ++u) {
      cf[u*4+0] = (_Float16)(f[u].x - mur[c*16 + u*4 + 0]);
      cf[u*4+1] = (_Float16)(f[u].y - mur[c*16 + u*4 + 1]);
      cf[u*4+2] = (_Float16)(f[u].z - mur[c*16 + u*4 + 2]);
      cf[u*4+3] = (_Float16)(f[u].w - mur[c*16 + u*4 + 3]);
    }
    *(f16x8*)(crow + c * 16)     = *(f16x8*)&cf[0];
    *(f16x8*)(crow + c * 16 + 8) = *(f16x8*)&cf[8];
    #pragma unroll
    for (int d = 0; d < 16; ++d) ct[(size_t)(c * 16 + d) * T_] = cf[d];
  }
}

// ---------------- kernel 3: flash attention, 32x32 MFMA, in-reg P -----------
// Swapped QK^T (C[key][q]); P->A-frag via cvt_pkrtz + permlane32_swap (T12);
// l via ones-B MFMA (lands in acc-row layout); defer-max (T13).
__global__ __launch_bounds__(256, 3)
void attn3_kernel(const _Float16* __restrict__ c16,
                  const _Float16* __restrict__ ct16,
                  const float* __restrict__ mu,
                  float* __restrict__ out) {
  __shared__ __align__(16) _Float16 Kb[2][64 * 64];
  __shared__ __align__(16) _Float16 Vb[2][64 * 64];

  const int tid  = threadIdx.x;
  const int lane = tid & 63;
  const int wv   = tid >> 6;
  const int c    = lane & 31;     // C col: q (QK) / d (PV); frag row index
  const int hp   = lane >> 5;     // lane half

  // XCD swizzle: 16 q-tile blocks of one (b,h) share an XCD
  const int bid = blockIdx.x;
  const int wid = (bid & 7) * 128 + (bid >> 3);
  const int qb  = wid & 15;
  const int bh  = wid >> 4;
  const int b   = bh >> 4;
  const int h   = bh & 15;

  const int q0w = qb * QB + wv * 32;

  // ---- Q B-frags (registers, whole kernel): col=q=c, k=d=16s+8hp+e ----
  f16x8 qf[4];
  {
    const _Float16* qrow = c16 + ((size_t)(b * T_ + q0w + c)) * D_ + h * HD_ + 8 * hp;
    #pragma unroll
    for (int s = 0; s < 4; ++s) qf[s] = *(const f16x8*)(qrow + 16 * s);
  }

  // staging source (pre-swizzled granule: cp = (lane&7) ^ (destrow&7))
  const int srow = wv * 16 + (lane >> 3);
  const int cp   = (lane & 7) ^ ((lane >> 3) & 7);
  const char* ksrc = (const char*)c16 +
      (((size_t)(b * T_) + srow) * D_ + h * HD_) * 2 + cp * 16;
  const char* vsrc = (const char*)ct16 +
      (((size_t)(bh * HD_) + srow) * T_) * 2 + cp * 16;

  // LDS fragment offsets (elements); same for K and V (same layout)
  int off[2][4];
  #pragma unroll
  for (int kt = 0; kt < 2; ++kt)
    #pragma unroll
    for (int s = 0; s < 4; ++s)
      off[kt][s] = (32 * kt + c) * 64 + 8 * ((2 * s + hp) ^ (c & 7));

  f32x16 acc0 = zero16(), acc1 = zero16(), lsum = zero16();
  float mrun = -3e38f;

  f16x8 onesb;
  #pragma unroll
  for (int e = 0; e < 8; ++e) onesb[e] = (_Float16)1.0f;

  // prologue: stage tile 0
  gld16(ksrc,                       &Kb[0][(wv * 16    ) * 64]);
  gld16(ksrc + (size_t)8 * D_ * 2,  &Kb[0][(wv * 16 + 8) * 64]);
  gld16(vsrc,                       &Vb[0][(wv * 16    ) * 64]);
  gld16(vsrc + (size_t)8 * T_ * 2,  &Vb[0][(wv * 16 + 8) * 64]);
  __syncthreads();

  int buf = 0;
  for (int step = 0; step < NSTEP; ++step) {
    // ---- issue next-tile staging (overlaps compute) ----
    if (step + 1 < NSTEP) {
      const char* k1 = ksrc + (size_t)(step + 1) * (KB * D_ * 2);
      const char* v1 = vsrc + (size_t)(step + 1) * (KB * 2);
      gld16(k1,                      &Kb[buf ^ 1][(wv * 16    ) * 64]);
      gld16(k1 + (size_t)8 * D_ * 2, &Kb[buf ^ 1][(wv * 16 + 8) * 64]);
      gld16(v1,                      &Vb[buf ^ 1][(wv * 16    ) * 64]);
      gld16(v1 + (size_t)8 * T_ * 2, &Vb[buf ^ 1][(wv * 16 + 8) * 64]);
    }
    const _Float16* Kp = &Kb[buf][0];
    const _Float16* Vp = &Vb[buf][0];

    // ---- S^T = K · Q^T : 2 C-tiles (keys 0-31, 32-63) x 4 k-slices ----
    f32x16 s0 = zero16(), s1 = zero16();
    __builtin_amdgcn_s_setprio(1);
    #pragma unroll
    for (int s = 0; s < 4; ++s) s0 = mfma32(*(const f16x8*)&Kp[off[0][s]], qf[s], s0);
    #pragma unroll
    for (int s = 0; s < 4; ++s) s1 = mfma32(*(const f16x8*)&Kp[off[1][s]], qf[s], s1);
    __builtin_amdgcn_s_setprio(0);

    // ---- row max (lane holds 32 vals of col q=c) ----
    float pm = fmaxf(s0[0], s0[1]);
    #pragma unroll
    for (int r = 2; r < 16; r += 2) pm = __builtin_fmaxf(__builtin_fmaxf(s0[r], s0[r+1]), pm);
    #pragma unroll
    for (int r = 0; r < 16; r += 2) pm = __builtin_fmaxf(__builtin_fmaxf(s1[r], s1[r+1]), pm);
    pm = fmaxf(pm, __shfl_xor(pm, 32));

    // ---- defer-max: rescale only when tile max jumps ----
    if (!__all(pm <= mrun + THR)) {
      const float mn = fmaxf(mrun, pm);
      const float al = exp2f((mrun - mn) * L2E);
      mrun = mn;
      #pragma unroll
      for (int r = 0; r < 16; ++r) {
        const int row = (r & 3) + 8 * (r >> 2) + 4 * hp;
        const float a = __shfl(al, row);
        acc0[r] *= a; acc1[r] *= a; lsum[r] *= a;
      }
    }

    // ---- P = exp2((S - m)*log2e) ----
    const float c1 = -mrun * L2E;
    float p0[16], p1[16];
    #pragma unroll
    for (int r = 0; r < 16; ++r) p0[r] = exp2f(fmaf(s0[r], L2E, c1));
    #pragma unroll
    for (int r = 0; r < 16; ++r) p1[r] = exp2f(fmaf(s1[r], L2E, c1));

    // ---- P -> A-frags: 16 cvt_pkrtz + 8 permlane32_swap ----
    f16x8 pa[4];
    #pragma unroll
    for (int kt = 0; kt < 2; ++kt) {
      const float* pp = kt ? p1 : p0;
      #pragma unroll
      for (int v = 0; v < 2; ++v) {
        uint32_t A0 = pkrtz(pp[8*v+0], pp[8*v+1]);
        uint32_t A1 = pkrtz(pp[8*v+2], pp[8*v+3]);
        uint32_t B0 = pkrtz(pp[8*v+4], pp[8*v+5]);
        uint32_t B1 = pkrtz(pp[8*v+6], pp[8*v+7]);
        pl32swap(A0, B0);   // A0 -> (e0,e1), B0 -> (e4,e5)
        pl32swap(A1, B1);   // A1 -> (e2,e3), B1 -> (e6,e7)
        pa[2*kt+v] = mk_frag(A0, A1, B0, B1);
      }
    }

    // ---- O += P·V (2 d-tiles) ; l += P·ones ----
    __builtin_amdgcn_s_setprio(1);
    #pragma unroll
    for (int s = 0; s < 4; ++s) acc0 = mfma32(pa[s], *(const f16x8*)&Vp[off[0][s]], acc0);
    #pragma unroll
    for (int s = 0; s < 4; ++s) acc1 = mfma32(pa[s], *(const f16x8*)&Vp[off[1][s]], acc1);
    #pragma unroll
    for (int s = 0; s < 4; ++s) lsum = mfma32(pa[s], onesb, lsum);
    __builtin_amdgcn_s_setprio(0);

    __syncthreads();   // drains gld16 (vmcnt0) + all waves' LDS reads
    buf ^= 1;
  }

  // ---- epilogue: out = acc / l + mu  (lsum already in acc-row layout) ----
  const float mv0 = mu[b * D_ + h * HD_ + c];
  const float mv1 = mu[b * D_ + h * HD_ + 32 + c];
  #pragma unroll
  for (int r = 0; r < 16; ++r) {
    const int q = q0w + (r & 3) + 8 * (r >> 2) + 4 * hp;
    const float li = 1.0f / lsum[r];
    float* orow = out + (size_t)(b * T_ + q) * D_ + h * HD_;
    orow[c]      = acc0[r] * li + mv0;
    orow[32 + c] = acc1[r] * li + mv1;
  }
}

// ---------------- fallback: verified round-1 kernel (small ws) --------------
__global__ __launch_bounds__(256)
void attn_fb_kernel(const float* __restrict__ x, const float* __restrict__ mu,
                    float* __restrict__ out) {
  __shared__ __align__(16) _Float16 Kt[64 * 64];
  __shared__ __align__(16) _Float16 Vt[64 * 64];
  __shared__ __align__(16) _Float16 Pl[4][2][16 * 64];

  const int tid  = threadIdx.x;
  const int lane = tid & 63;
  const int wv   = tid >> 6;
  const int j    = lane & 15;
  const int g    = lane >> 4;

  const int qb = blockIdx.x & 15;
  const int bh = blockIdx.x >> 4;
  const int b  = bh >> 4;
  const int h  = bh & 15;

  const float* xb  = x  + (size_t)b * T_ * D_;
  const float* muh = mu + b * D_ + h * HD_;

  f16x8 qf[2][2];
  const int q0 = qb * QB + wv * 32;
  #pragma unroll
  for (int qt = 0; qt < 2; ++qt) {
    const float* qrow = xb + (size_t)(q0 + qt * 16 + j) * D_ + h * HD_;
    #pragma unroll
    for (int ks = 0; ks < 2; ++ks) {
      const int d0 = ks * 32 + g * 8;
      float4 a  = *(const float4*)(qrow + d0);
      float4 cc = *(const float4*)(qrow + d0 + 4);
      float4 m0 = *(const float4*)(muh + d0);
      float4 m1 = *(const float4*)(muh + d0 + 4);
      f16x8 f;
      f[0] = (_Float16)(a.x - m0.x); f[1] = (_Float16)(a.y - m0.y);
      f[2] = (_Float16)(a.z - m0.z); f[3] = (_Float16)(a.w - m0.w);
      f[4] = (_Float16)(cc.x - m1.x); f[5] = (_Float16)(cc.y - m1.y);
      f[6] = (_Float16)(cc.z - m1.z); f[7] = (_Float16)(cc.w - m1.w);
      qf[qt][ks] = f;
    }
  }

  const int kd0 = (tid & 7) * 8;
  const float4 kmu0 = *(const float4*)(muh + kd0);
  const float4 kmu1 = *(const float4*)(muh + kd0 + 4);
  const int vd2 = (tid & 31) * 2;
  const int vkc = tid >> 5;

  f32x4 acc[2][4];
  float mrun[2][4], lrun[2][4];
  #pragma unroll
  for (int qt = 0; qt < 2; ++qt) {
    #pragma unroll
    for (int n = 0; n < 4; ++n) acc[qt][n] = f32x4{0.f, 0.f, 0.f, 0.f};
    #pragma unroll
    for (int r = 0; r < 4; ++r) { mrun[qt][r] = -1e30f; lrun[qt][r] = 0.f; }
  }

  const int swj = (j & 7) << 3;

  for (int step = 0; step < NSTEP; ++step) {
    const size_t krow0 = (size_t)(step * KB) * D_ + h * HD_;
    __syncthreads();

    #pragma unroll
    for (int cc2 = 0; cc2 < 2; ++cc2) {
      const int kk = (tid >> 3) + cc2 * 32;
      const float* src = xb + krow0 + (size_t)kk * D_ + kd0;
      float4 a = *(const float4*)src;
      float4 cc = *(const float4*)(src + 4);
      f16x8 f;
      f[0] = (_Float16)(a.x - kmu0.x); f[1] = (_Float16)(a.y - kmu0.y);
      f[2] = (_Float16)(a.z - kmu0.z); f[3] = (_Float16)(a.w - kmu0.w);
      f[4] = (_Float16)(cc.x - kmu1.x); f[5] = (_Float16)(cc.y - kmu1.y);
      f[6] = (_Float16)(cc.z - kmu1.z); f[7] = (_Float16)(cc.w - kmu1.w);
      *(f16x8*)&Kt[kk * 64 + (kd0 ^ ((kk & 7) << 3))] = f;
    }
    {
      float2 t[8];
      #pragma unroll
      for (int e = 0; e < 8; ++e)
        t[e] = *(const float2*)(xb + krow0 + (size_t)(vkc * 8 + e) * D_ + vd2);
      f16x8 f0, f1;
      #pragma unroll
      for (int e = 0; e < 8; ++e) { f0[e] = (_Float16)t[e].x; f1[e] = (_Float16)t[e].y; }
      *(f16x8*)&Vt[(vd2    ) * 64 + ((vkc * 8) ^ (((vd2    ) & 7) << 3))] = f0;
      *(f16x8*)&Vt[(vd2 + 1) * 64 + ((vkc * 8) ^ (((vd2 + 1) & 7) << 3))] = f1;
    }
    __syncthreads();

    f32x4 s[2][4];
    #pragma unroll
    for (int n = 0; n < 4; ++n) {
      const int rb = (n * 16 + j) * 64;
      f16x8 kb0 = *(const f16x8*)&Kt[rb + (((     g * 8)) ^ swj)];
      f16x8 kb1 = *(const f16x8*)&Kt[rb + (((32 + g * 8)) ^ swj)];
      #pragma unroll
      for (int qt = 0; qt < 2; ++qt) {
        f32x4 z = f32x4{0.f, 0.f, 0.f, 0.f};
        z = mfma16(qf[qt][0], kb0, z);
        s[qt][n] = mfma16(qf[qt][1], kb1, z);
      }
    }

    #pragma unroll
    for (int qt = 0; qt < 2; ++qt) {
      float al[4];
      #pragma unroll
      for (int r = 0; r < 4; ++r) {
        float v = fmaxf(fmaxf(s[qt][0][r], s[qt][1][r]),
                        fmaxf(s[qt][2][r], s[qt][3][r]));
        v = fmaxf(v, __shfl_xor(v, 1, 16));
        v = fmaxf(v, __shfl_xor(v, 2, 16));
        v = fmaxf(v, __shfl_xor(v, 4, 16));
        v = fmaxf(v, __shfl_xor(v, 8, 16));
        const float mn = fmaxf(mrun[qt][r], v);
        al[r] = exp2f((mrun[qt][r] - mn) * L2E);
        mrun[qt][r] = mn;
        float p0 = exp2f((s[qt][0][r] - mn) * L2E);
        float p1 = exp2f((s[qt][1][r] - mn) * L2E);
        float p2 = exp2f((s[qt][2][r] - mn) * L2E);
        float p3 = exp2f((s[qt][3][r] - mn) * L2E);
        float rs = (p0 + p1) + (p2 + p3);
        rs += __shfl_xor(rs, 1, 16);
        rs += __shfl_xor(rs, 2, 16);
        rs += __shfl_xor(rs, 4, 16);
        rs += __shfl_xor(rs, 8, 16);
        lrun[qt][r] = lrun[qt][r] * al[r] + rs;
        const int q   = g * 4 + r;
        const int qsw = (q & 7) << 3;
        _Float16* prow = &Pl[wv][qt][q * 64];
        prow[(     j) ^ qsw] = (_Float16)p0;
        prow[(16 + j) ^ qsw] = (_Float16)p1;
        prow[(32 + j) ^ qsw] = (_Float16)p2;
        prow[(48 + j) ^ qsw] = (_Float16)p3;
      }
      #pragma unroll
      for (int n = 0; n < 4; ++n) {
        acc[qt][n][0] *= al[0]; acc[qt][n][1] *= al[1];
        acc[qt][n][2] *= al[2]; acc[qt][n][3] *= al[3];
      }
    }

    asm volatile("s_waitcnt lgkmcnt(0)" ::: "memory");

    f16x8 pa[2][2];
    #pragma unroll
    for (int qt = 0; qt < 2; ++qt) {
      const _Float16* Pw = &Pl[wv][qt][0];
      pa[qt][0] = *(const f16x8*)&Pw[j * 64 + (((     g * 8)) ^ swj)];
      pa[qt][1] = *(const f16x8*)&Pw[j * 64 + (((32 + g * 8)) ^ swj)];
    }
    #pragma unroll
    for (int n = 0; n < 4; ++n) {
      const int rb = (n * 16 + j) * 64;
      f16x8 v0 = *(const f16x8*)&Vt[rb + (((     g * 8)) ^ swj)];
      f16x8 v1 = *(const f16x8*)&Vt[rb + (((32 + g * 8)) ^ swj)];
      #pragma unroll
      for (int qt = 0; qt < 2; ++qt) {
        acc[qt][n] = mfma16(pa[qt][0], v0, acc[qt][n]);
        acc[qt][n] = mfma16(pa[qt][1], v1, acc[qt][n]);
      }
    }
  }

  #pragma unroll
  for (int qt = 0; qt < 2; ++qt) {
    float inv[4];
    #pragma unroll
    for (int r = 0; r < 4; ++r) inv[r] = 1.0f / lrun[qt][r];
    #pragma unroll
    for (int n = 0; n < 4; ++n) {
      #pragma unroll
      for (int r = 0; r < 4; ++r) {
        const int q = q0 + qt * 16 + g * 4 + r;
        out[(size_t)(b * T_ + q) * D_ + h * HD_ + n * 16 + j] =
            acc[qt][n][r] * inv[r];
      }
    }
  }
}

extern "C" void kernel_launch(void* const* d_in, const int* in_sizes, int n_in,
                              void* d_out, int out_size, void* d_ws, size_t ws_size,
                              hipStream_t stream) {
  (void)in_sizes; (void)n_in; (void)out_size;
  const float* x  = (const float*)d_in[0];
  float* outp     = (float*)d_out;

  const size_t MU_BYTES  = (size_t)B_ * D_ * sizeof(float);     // 16 KB
  const size_t C16_BYTES = (size_t)B_ * T_ * D_ * 2;            // 16 MB

  float* mu = (float*)d_ws;
  hipLaunchKernelGGL(colmean_kernel, dim3(B_ * 64), dim3(256), 0, stream, x, mu);

  if (ws_size >= MU_BYTES + 2 * C16_BYTES) {
    _Float16* c16  = (_Float16*)((char*)d_ws + MU_BYTES);
    _Float16* ct16 = (_Float16*)((char*)d_ws + MU_BYTES + C16_BYTES);
    hipLaunchKernelGGL(cvt_kernel, dim3(512), dim3(256), 0, stream, x, mu, c16, ct16);
    hipLaunchKernelGGL(attn3_kernel, dim3((T_ / QB) * B_ * H_), dim3(256), 0, stream,
                       c16, ct16, mu, outp);
  } else {
    hipLaunchKernelGGL(attn_fb_kernel, dim3((T_ / QB) * B_ * H_), dim3(256), 0, stream,
                       x, mu, outp);
  }
}

// Round 5
// 143.291 us; speedup vs baseline: 2.8084x; 1.1100x over previous
//
#include <hip/hip_runtime.h>
#include <stdint.h>

// x: [B=4][T=2048][D=1024] fp32, H=16 heads, hd=64.
#define B_   4
#define T_   2048
#define H_   16
#define HD_  64
#define D_   1024
#define QB   128              // query rows per block (4 waves x 32)
#define KB   64               // key rows per KV step
#define NSTEP (T_ / KB)       // 32
#define L2E   1.44269504088896f
#define THR   11.0f           // defer-max threshold (P <= e^11 < f16 max)
#define MINIT 20.0f           // initial running max (check still triggers if exceeded)

typedef __attribute__((ext_vector_type(4)))  float    f32x4;
typedef __attribute__((ext_vector_type(16))) float    f32x16;
typedef __attribute__((ext_vector_type(8)))  _Float16 f16x8;
typedef __attribute__((ext_vector_type(2)))  __fp16   h16x2;   // builtin-native f16x2

__device__ __forceinline__ f32x4 mfma16(f16x8 a, f16x8 b, f32x4 c) {
  return __builtin_amdgcn_mfma_f32_16x16x32_f16(a, b, c, 0, 0, 0);
}
__device__ __forceinline__ f32x16 mfma32(f16x8 a, f16x8 b, f32x16 c) {
  return __builtin_amdgcn_mfma_f32_32x32x16_f16(a, b, c, 0, 0, 0);
}
__device__ __forceinline__ f32x16 zero16() {
  f32x16 z;
  #pragma unroll
  for (int i = 0; i < 16; ++i) z[i] = 0.f;
  return z;
}
__device__ __forceinline__ uint32_t pkrtz_u(float a, float b) {
  h16x2 r = __builtin_amdgcn_cvt_pkrtz(a, b);
  return __builtin_bit_cast(uint32_t, r);
}
__device__ __forceinline__ float fdot2_u(uint32_t a, h16x2 ones, float c) {
  return __builtin_amdgcn_fdot2(__builtin_bit_cast(h16x2, a), ones, c, false);
}
// v_permlane32_swap_b32 d, s: d's upper 32 lanes <-> s's lower 32 lanes.
__device__ __forceinline__ void pl32swap(uint32_t& a, uint32_t& b) {
  asm volatile("v_permlane32_swap_b32 %0, %1" : "+v"(a), "+v"(b));
}
__device__ __forceinline__ f16x8 mk_frag(uint32_t u0, uint32_t u1,
                                         uint32_t u2, uint32_t u3) {
  union { uint32_t u[4]; f16x8 v; } x;
  x.u[0] = u0; x.u[1] = u1; x.u[2] = u2; x.u[3] = u3;
  return x.v;
}
// async global->LDS, 16B/lane; LDS dest = wave-uniform base + lane*16
__device__ __forceinline__ void gld16(const void* g, void* l) {
  __builtin_amdgcn_global_load_lds(
      (const __attribute__((address_space(1))) uint32_t*)g,
      (__attribute__((address_space(3))) uint32_t*)l, 16, 0, 0);
}

// ---------------- kernel 1: per-(b,d) column mean over T --------------------
__global__ __launch_bounds__(256)
void colmean_kernel(const float* __restrict__ x, float* __restrict__ mu) {
  const int b   = blockIdx.x >> 6;
  const int c0  = (blockIdx.x & 63) << 4;
  const int col = threadIdx.x & 15;
  const int rg  = threadIdx.x >> 4;
  const float* p = x + ((size_t)(b * T_ + rg * 128)) * D_ + c0 + col;
  float s = 0.f;
  #pragma unroll 8
  for (int r = 0; r < 128; ++r) s += p[(size_t)r * D_];
  __shared__ float red[16][17];
  red[rg][col] = s;
  __syncthreads();
  if (rg == 0) {
    float t = 0.f;
    #pragma unroll
    for (int i = 0; i < 16; ++i) t += red[i][col];
    mu[b * D_ + c0 + col] = t * (1.f / (float)T_);
  }
}

// ---------------- kernel 2: centered f16, PLANE-MAJOR tiled layouts ---------
// KT [bh][tile 32][plane=d-granule 8][row=key 64][8 f16]  (8KB per tile)
// VT [bh][tile 32][plane=key-granule 8][row=d 64][8 f16]
__global__ __launch_bounds__(256)
void cvt2_kernel(const float* __restrict__ x, const float* __restrict__ mu,
                 _Float16* __restrict__ KT, _Float16* __restrict__ VT) {
  const int unit = blockIdx.x * 4 + (threadIdx.x >> 6);  // 0..2047
  const int bh   = unit >> 5;
  const int tile = unit & 31;
  const int b    = bh >> 4;
  const int h    = bh & 15;
  const int lane = threadIdx.x & 63;
  const int t    = tile * 64 + lane;

  const float* xr  = x  + ((size_t)(b * T_ + t)) * D_ + h * HD_;
  const float* mur = mu + b * D_ + h * HD_;

  _Float16 cf[64];
  #pragma unroll
  for (int u = 0; u < 16; ++u) {
    float4 f = *(const float4*)(xr + u * 4);
    float4 m = *(const float4*)(mur + u * 4);
    cf[u*4+0] = (_Float16)(f.x - m.x);
    cf[u*4+1] = (_Float16)(f.y - m.y);
    cf[u*4+2] = (_Float16)(f.z - m.z);
    cf[u*4+3] = (_Float16)(f.w - m.w);
  }
  // K: plane g holds d-granule g of all 64 rows; lane = row -> coalesced 16B
  _Float16* kt = KT + ((size_t)(bh * 32 + tile)) * 4096;
  #pragma unroll
  for (int g = 0; g < 8; ++g)
    *(f16x8*)&kt[g * 512 + lane * 8] = *(const f16x8*)&cf[g * 8];
  // V: plane = key-granule (lane>>3), row = d, elem-in-granule = lane&7
  _Float16* vt = VT + ((size_t)(bh * 32 + tile)) * 4096 + (lane >> 3) * 512 + (lane & 7);
  #pragma unroll
  for (int d = 0; d < 64; ++d) vt[d * 8] = cf[d];
}

// ---------------- kernel 3: flash attention, plane-major LDS ----------------
__global__ __launch_bounds__(256, 4)
void attn4_kernel(const _Float16* __restrict__ KT,
                  const _Float16* __restrict__ VT,
                  const float* __restrict__ mu,
                  float* __restrict__ out) {
  __shared__ __align__(16) _Float16 Kb[2][4096];
  __shared__ __align__(16) _Float16 Vb[2][4096];

  const int tid  = threadIdx.x;
  const int lane = tid & 63;
  const int wv   = tid >> 6;
  const int c    = lane & 31;     // frag row/col index
  const int hp   = lane >> 5;     // lane half

  // XCD swizzle: 16 q-tile blocks of one (b,h) share an XCD
  const int bid = blockIdx.x;
  const int wid = (bid & 7) * 128 + (bid >> 3);
  const int qb  = wid & 15;
  const int bh  = wid >> 4;
  const int b   = bh >> 4;
  const int h   = bh & 15;

  const int q0w = qb * QB + wv * 32;

  // ---- Q B-frags from KT (col=q=c, k=d=16s+8hp+e) ----
  f16x8 qf[4];
  {
    const _Float16* qt = KT + ((size_t)(bh * 32 + (q0w >> 6))) * 4096;
    const int qrow = ((wv & 1) * 32) + c;
    #pragma unroll
    for (int s = 0; s < 4; ++s)
      qf[s] = *(const f16x8*)&qt[(2 * s + hp) * 512 + qrow * 8];
  }

  // staging sources: wave wv stages K planes {2wv,2wv+1}, V planes {2wv,2wv+1}
  const char* ksrc = (const char*)KT + ((size_t)(bh * 32)) * 8192 + wv * 2048 + lane * 16;
  const char* vsrc = (const char*)VT + ((size_t)(bh * 32)) * 8192 + wv * 2048 + lane * 16;

  const int fb = hp * 512 + c * 8;   // frag base (elems); +s*1024 +kt*256

  f32x16 acc0 = zero16(), acc1 = zero16();
  float mrun = MINIT, lrun = 0.f;
  h16x2 one2; one2[0] = (__fp16)1.0f; one2[1] = (__fp16)1.0f;

  // prologue: stage tile 0
  gld16(ksrc,        &Kb[0][wv * 1024]);
  gld16(ksrc + 1024, &Kb[0][wv * 1024 + 512]);
  gld16(vsrc,        &Vb[0][wv * 1024]);
  gld16(vsrc + 1024, &Vb[0][wv * 1024 + 512]);
  ksrc += 8192; vsrc += 8192;
  __syncthreads();

  int buf = 0;
  for (int step = 0; step < NSTEP; ++step) {
    if (step + 1 < NSTEP) {
      gld16(ksrc,        &Kb[buf ^ 1][wv * 1024]);
      gld16(ksrc + 1024, &Kb[buf ^ 1][wv * 1024 + 512]);
      gld16(vsrc,        &Vb[buf ^ 1][wv * 1024]);
      gld16(vsrc + 1024, &Vb[buf ^ 1][wv * 1024 + 512]);
      ksrc += 8192; vsrc += 8192;
    }
    const _Float16* Kp = &Kb[buf][fb];
    const _Float16* Vp = &Vb[buf][fb];

    #pragma unroll
    for (int kt = 0; kt < 2; ++kt) {
      // ---- S-tile = K[32kt..+31] · Q^T : C[row=key][col=q] ----
      f32x16 st = zero16();
      __builtin_amdgcn_s_setprio(1);
      #pragma unroll
      for (int s = 0; s < 4; ++s)
        st = mfma32(*(const f16x8*)&Kp[s * 1024 + kt * 256], qf[s], st);
      __builtin_amdgcn_s_setprio(0);

      // ---- row max (16 vals here + hp-partner) ----
      float pm = fmaxf(st[0], st[1]);
      #pragma unroll
      for (int r = 2; r < 16; r += 2) pm = fmaxf(fmaxf(st[r], st[r + 1]), pm);
      pm = fmaxf(pm, __shfl_xor(pm, 32));

      // ---- defer-max rescale (rare) ----
      if (!__all(pm <= mrun + THR)) {
        const float mn = fmaxf(mrun, pm);
        const float al = exp2f((mrun - mn) * L2E);
        mrun = mn;
        lrun *= al;
        #pragma unroll
        for (int r = 0; r < 16; ++r) {
          const int row = (r & 3) + 8 * (r >> 2) + 4 * hp;
          const float a = __shfl(al, row);
          acc0[r] *= a; acc1[r] *= a;
        }
      }

      // ---- P = exp2((S-m)*L2E); pack -> A-frags; row-sum via dot2 ----
      const float c1 = -mrun * L2E;
      float rs = 0.f;
      f16x8 paL, paH;
      #pragma unroll
      for (int v = 0; v < 2; ++v) {
        uint32_t A0 = pkrtz_u(exp2f(fmaf(st[8*v+0], L2E, c1)),
                              exp2f(fmaf(st[8*v+1], L2E, c1)));
        uint32_t A1 = pkrtz_u(exp2f(fmaf(st[8*v+2], L2E, c1)),
                              exp2f(fmaf(st[8*v+3], L2E, c1)));
        uint32_t B0 = pkrtz_u(exp2f(fmaf(st[8*v+4], L2E, c1)),
                              exp2f(fmaf(st[8*v+5], L2E, c1)));
        uint32_t B1 = pkrtz_u(exp2f(fmaf(st[8*v+6], L2E, c1)),
                              exp2f(fmaf(st[8*v+7], L2E, c1)));
        rs = fdot2_u(A0, one2, rs); rs = fdot2_u(A1, one2, rs);
        rs = fdot2_u(B0, one2, rs); rs = fdot2_u(B1, one2, rs);
        pl32swap(A0, B0);
        pl32swap(A1, B1);
        if (v == 0) paL = mk_frag(A0, A1, B0, B1);
        else        paH = mk_frag(A0, A1, B0, B1);
      }
      lrun += rs + __shfl_xor(rs, 32);

      // ---- O += P-slice · V (slices s'=2kt, 2kt+1) ----
      __builtin_amdgcn_s_setprio(1);
      acc0 = mfma32(paL, *(const f16x8*)&Vp[(2*kt    ) * 1024      ], acc0);
      acc0 = mfma32(paH, *(const f16x8*)&Vp[(2*kt + 1) * 1024      ], acc0);
      acc1 = mfma32(paL, *(const f16x8*)&Vp[(2*kt    ) * 1024 + 256], acc1);
      acc1 = mfma32(paH, *(const f16x8*)&Vp[(2*kt + 1) * 1024 + 256], acc1);
      __builtin_amdgcn_s_setprio(0);
    }

    __syncthreads();   // drains gld16 (vmcnt0) + all waves' LDS reads
    buf ^= 1;
  }

  // ---- epilogue: out = acc / l + mu ----
  const float mv0 = mu[b * D_ + h * HD_ + c];
  const float mv1 = mu[b * D_ + h * HD_ + 32 + c];
  const float linv = 1.0f / lrun;
  #pragma unroll
  for (int r = 0; r < 16; ++r) {
    const int row = (r & 3) + 8 * (r >> 2) + 4 * hp;
    const float lr = __shfl(linv, row);
    const int q = q0w + row;
    float* orow = out + (size_t)(b * T_ + q) * D_ + h * HD_;
    orow[c]      = acc0[r] * lr + mv0;
    orow[32 + c] = acc1[r] * lr + mv1;
  }
}

// ---------------- fallback: verified round-1 kernel (small ws) --------------
__global__ __launch_bounds__(256)
void attn_fb_kernel(const float* __restrict__ x, const float* __restrict__ mu,
                    float* __restrict__ out) {
  __shared__ __align__(16) _Float16 Kt[64 * 64];
  __shared__ __align__(16) _Float16 Vt[64 * 64];
  __shared__ __align__(16) _Float16 Pl[4][2][16 * 64];

  const int tid  = threadIdx.x;
  const int lane = tid & 63;
  const int wv   = tid >> 6;
  const int j    = lane & 15;
  const int g    = lane >> 4;

  const int qb = blockIdx.x & 15;
  const int bh = blockIdx.x >> 4;
  const int b  = bh >> 4;
  const int h  = bh & 15;

  const float* xb  = x  + (size_t)b * T_ * D_;
  const float* muh = mu + b * D_ + h * HD_;

  f16x8 qf[2][2];
  const int q0 = qb * QB + wv * 32;
  #pragma unroll
  for (int qt = 0; qt < 2; ++qt) {
    const float* qrow = xb + (size_t)(q0 + qt * 16 + j) * D_ + h * HD_;
    #pragma unroll
    for (int ks = 0; ks < 2; ++ks) {
      const int d0 = ks * 32 + g * 8;
      float4 a  = *(const float4*)(qrow + d0);
      float4 cc = *(const float4*)(qrow + d0 + 4);
      float4 m0 = *(const float4*)(muh + d0);
      float4 m1 = *(const float4*)(muh + d0 + 4);
      f16x8 f;
      f[0] = (_Float16)(a.x - m0.x); f[1] = (_Float16)(a.y - m0.y);
      f[2] = (_Float16)(a.z - m0.z); f[3] = (_Float16)(a.w - m0.w);
      f[4] = (_Float16)(cc.x - m1.x); f[5] = (_Float16)(cc.y - m1.y);
      f[6] = (_Float16)(cc.z - m1.z); f[7] = (_Float16)(cc.w - m1.w);
      qf[qt][ks] = f;
    }
  }

  const int kd0 = (tid & 7) * 8;
  const float4 kmu0 = *(const float4*)(muh + kd0);
  const float4 kmu1 = *(const float4*)(muh + kd0 + 4);
  const int vd2 = (tid & 31) * 2;
  const int vkc = tid >> 5;

  f32x4 acc[2][4];
  float mrun[2][4], lrun[2][4];
  #pragma unroll
  for (int qt = 0; qt < 2; ++qt) {
    #pragma unroll
    for (int n = 0; n < 4; ++n) acc[qt][n] = f32x4{0.f, 0.f, 0.f, 0.f};
    #pragma unroll
    for (int r = 0; r < 4; ++r) { mrun[qt][r] = -1e30f; lrun[qt][r] = 0.f; }
  }

  const int swj = (j & 7) << 3;

  for (int step = 0; step < NSTEP; ++step) {
    const size_t krow0 = (size_t)(step * KB) * D_ + h * HD_;
    __syncthreads();

    #pragma unroll
    for (int cc2 = 0; cc2 < 2; ++cc2) {
      const int kk = (tid >> 3) + cc2 * 32;
      const float* src = xb + krow0 + (size_t)kk * D_ + kd0;
      float4 a = *(const float4*)src;
      float4 cc = *(const float4*)(src + 4);
      f16x8 f;
      f[0] = (_Float16)(a.x - kmu0.x); f[1] = (_Float16)(a.y - kmu0.y);
      f[2] = (_Float16)(a.z - kmu0.z); f[3] = (_Float16)(a.w - kmu0.w);
      f[4] = (_Float16)(cc.x - kmu1.x); f[5] = (_Float16)(cc.y - kmu1.y);
      f[6] = (_Float16)(cc.z - kmu1.z); f[7] = (_Float16)(cc.w - kmu1.w);
      *(f16x8*)&Kt[kk * 64 + (kd0 ^ ((kk & 7) << 3))] = f;
    }
    {
      float2 t[8];
      #pragma unroll
      for (int e = 0; e < 8; ++e)
        t[e] = *(const float2*)(xb + krow0 + (size_t)(vkc * 8 + e) * D_ + vd2);
      f16x8 f0, f1;
      #pragma unroll
      for (int e = 0; e < 8; ++e) { f0[e] = (_Float16)t[e].x; f1[e] = (_Float16)t[e].y; }
      *(f16x8*)&Vt[(vd2    ) * 64 + ((vkc * 8) ^ (((vd2    ) & 7) << 3))] = f0;
      *(f16x8*)&Vt[(vd2 + 1) * 64 + ((vkc * 8) ^ (((vd2 + 1) & 7) << 3))] = f1;
    }
    __syncthreads();

    f32x4 s[2][4];
    #pragma unroll
    for (int n = 0; n < 4; ++n) {
      const int rb = (n * 16 + j) * 64;
      f16x8 kb0 = *(const f16x8*)&Kt[rb + (((     g * 8)) ^ swj)];
      f16x8 kb1 = *(const f16x8*)&Kt[rb + (((32 + g * 8)) ^ swj)];
      #pragma unroll
      for (int qt = 0; qt < 2; ++qt) {
        f32x4 z = f32x4{0.f, 0.f, 0.f, 0.f};
        z = mfma16(qf[qt][0], kb0, z);
        s[qt][n] = mfma16(qf[qt][1], kb1, z);
      }
    }

    #pragma unroll
    for (int qt = 0; qt < 2; ++qt) {
      float al[4];
      #pragma unroll
      for (int r = 0; r < 4; ++r) {
        float v = fmaxf(fmaxf(s[qt][0][r], s[qt][1][r]),
                        fmaxf(s[qt][2][r], s[qt][3][r]));
        v = fmaxf(v, __shfl_xor(v, 1, 16));
        v = fmaxf(v, __shfl_xor(v, 2, 16));
        v = fmaxf(v, __shfl_xor(v, 4, 16));
        v = fmaxf(v, __shfl_xor(v, 8, 16));
        const float mn = fmaxf(mrun[qt][r], v);
        al[r] = exp2f((mrun[qt][r] - mn) * L2E);
        mrun[qt][r] = mn;
        float p0 = exp2f((s[qt][0][r] - mn) * L2E);
        float p1 = exp2f((s[qt][1][r] - mn) * L2E);
        float p2 = exp2f((s[qt][2][r] - mn) * L2E);
        float p3 = exp2f((s[qt][3][r] - mn) * L2E);
        float rs = (p0 + p1) + (p2 + p3);
        rs += __shfl_xor(rs, 1, 16);
        rs += __shfl_xor(rs, 2, 16);
        rs += __shfl_xor(rs, 4, 16);
        rs += __shfl_xor(rs, 8, 16);
        lrun[qt][r] = lrun[qt][r] * al[r] + rs;
        const int q   = g * 4 + r;
        const int qsw = (q & 7) << 3;
        _Float16* prow = &Pl[wv][qt][q * 64];
        prow[(     j) ^ qsw] = (_Float16)p0;
        prow[(16 + j) ^ qsw] = (_Float16)p1;
        prow[(32 + j) ^ qsw] = (_Float16)p2;
        prow[(48 + j) ^ qsw] = (_Float16)p3;
      }
      #pragma unroll
      for (int n = 0; n < 4; ++n) {
        acc[qt][n][0] *= al[0]; acc[qt][n][1] *= al[1];
        acc[qt][n][2] *= al[2]; acc[qt][n][3] *= al[3];
      }
    }

    asm volatile("s_waitcnt lgkmcnt(0)" ::: "memory");

    f16x8 pa[2][2];
    #pragma unroll
    for (int qt = 0; qt < 2; ++qt) {
      const _Float16* Pw = &Pl[wv][qt][0];
      pa[qt][0] = *(const f16x8*)&Pw[j * 64 + (((     g * 8)) ^ swj)];
      pa[qt][1] = *(const f16x8*)&Pw[j * 64 + (((32 + g * 8)) ^ swj)];
    }
    #pragma unroll
    for (int n = 0; n < 4; ++n) {
      const int rb = (n * 16 + j) * 64;
      f16x8 v0 = *(const f16x8*)&Vt[rb + (((     g * 8)) ^ swj)];
      f16x8 v1 = *(const f16x8*)&Vt[rb + (((32 + g * 8)) ^ swj)];
      #pragma unroll
      for (int qt = 0; qt < 2; ++qt) {
        acc[qt][n] = mfma16(pa[qt][0], v0, acc[qt][n]);
        acc[qt][n] = mfma16(pa[qt][1], v1, acc[qt][n]);
      }
    }
  }

  #pragma unroll
  for (int qt = 0; qt < 2; ++qt) {
    float inv[4];
    #pragma unroll
    for (int r = 0; r < 4; ++r) inv[r] = 1.0f / lrun[qt][r];
    #pragma unroll
    for (int n = 0; n < 4; ++n) {
      #pragma unroll
      for (int r = 0; r < 4; ++r) {
        const int q = q0 + qt * 16 + g * 4 + r;
        out[(size_t)(b * T_ + q) * D_ + h * HD_ + n * 16 + j] =
            acc[qt][n][r] * inv[r];
      }
    }
  }
}

extern "C" void kernel_launch(void* const* d_in, const int* in_sizes, int n_in,
                              void* d_out, int out_size, void* d_ws, size_t ws_size,
                              hipStream_t stream) {
  (void)in_sizes; (void)n_in; (void)out_size;
  const float* x  = (const float*)d_in[0];
  float* outp     = (float*)d_out;

  const size_t MU_BYTES  = (size_t)B_ * D_ * sizeof(float);     // 16 KB
  const size_t C16_BYTES = (size_t)B_ * T_ * D_ * 2;            // 16 MB

  float* mu = (float*)d_ws;
  hipLaunchKernelGGL(colmean_kernel, dim3(B_ * 64), dim3(256), 0, stream, x, mu);

  if (ws_size >= MU_BYTES + 2 * C16_BYTES) {
    _Float16* KT = (_Float16*)((char*)d_ws + MU_BYTES);
    _Float16* VT = (_Float16*)((char*)d_ws + MU_BYTES + C16_BYTES);
    hipLaunchKernelGGL(cvt2_kernel, dim3(512), dim3(256), 0, stream, x, mu, KT, VT);
    hipLaunchKernelGGL(attn4_kernel, dim3((T_ / QB) * B_ * H_), dim3(256), 0, stream,
                       KT, VT, mu, outp);
  } else {
    hipLaunchKernelGGL(attn_fb_kernel, dim3((T_ / QB) * B_ * H_), dim3(256), 0, stream,
                       x, mu, outp);
  }
}

// Round 6
// 113.281 us; speedup vs baseline: 3.5524x; 1.2649x over previous
//
#include <hip/hip_runtime.h>
#include <stdint.h>

// x: [B=4][T=2048][D=1024] fp32, H=16 heads, hd=64.
#define B_   4
#define T_   2048
#define H_   16
#define HD_  64
#define D_   1024
#define QB   128              // query rows per block (4 waves x 32)
#define KB   64               // key rows per KV step
#define NSTEP (T_ / KB)       // 32
#define L2E   1.44269504088896f
#define SQL2E 1.20112240878645f   // sqrt(log2 e)
#define THR2  15.5f           // exp2-space guard: p <= 2^15.5 < f16 max
#define M2INIT 28.8539f       // 20 * L2E

typedef __attribute__((ext_vector_type(4)))  float    f32x4;
typedef __attribute__((ext_vector_type(16))) float    f32x16;
typedef __attribute__((ext_vector_type(8)))  _Float16 f16x8;
typedef __attribute__((ext_vector_type(2)))  __fp16   h16x2;   // builtin-native f16x2

__device__ __forceinline__ f32x4 mfma16(f16x8 a, f16x8 b, f32x4 c) {
  return __builtin_amdgcn_mfma_f32_16x16x32_f16(a, b, c, 0, 0, 0);
}
__device__ __forceinline__ f32x16 mfma32(f16x8 a, f16x8 b, f32x16 c) {
  return __builtin_amdgcn_mfma_f32_32x32x16_f16(a, b, c, 0, 0, 0);
}
__device__ __forceinline__ f32x16 zero16() {
  f32x16 z;
  #pragma unroll
  for (int i = 0; i < 16; ++i) z[i] = 0.f;
  return z;
}
__device__ __forceinline__ float fexp2(float x) {
#if __has_builtin(__builtin_amdgcn_exp2f)
  return __builtin_amdgcn_exp2f(x);
#else
  return exp2f(x);
#endif
}
__device__ __forceinline__ uint32_t pkrtz_u(float a, float b) {
  h16x2 r = __builtin_amdgcn_cvt_pkrtz(a, b);
  return __builtin_bit_cast(uint32_t, r);
}
__device__ __forceinline__ float fdot2_u(uint32_t a, h16x2 ones, float c) {
  return __builtin_amdgcn_fdot2(__builtin_bit_cast(h16x2, a), ones, c, false);
}
// v_permlane32_swap_b32 d, s: d's upper 32 lanes <-> s's lower 32 lanes.
__device__ __forceinline__ void pl32swap(uint32_t& a, uint32_t& b) {
  asm volatile("v_permlane32_swap_b32 %0, %1" : "+v"(a), "+v"(b));
}
__device__ __forceinline__ f16x8 mk_frag(uint32_t u0, uint32_t u1,
                                         uint32_t u2, uint32_t u3) {
  union { uint32_t u[4]; f16x8 v; } x;
  x.u[0] = u0; x.u[1] = u1; x.u[2] = u2; x.u[3] = u3;
  return x.v;
}
// async global->LDS, 16B/lane; LDS dest = wave-uniform base + lane*16
__device__ __forceinline__ void gld16(const void* g, void* l) {
  __builtin_amdgcn_global_load_lds(
      (const __attribute__((address_space(1))) uint32_t*)g,
      (__attribute__((address_space(3))) uint32_t*)l, 16, 0, 0);
}

// ---------------- kernel 1: per-(b,d) column mean over T --------------------
__global__ __launch_bounds__(256)
void colmean_kernel(const float* __restrict__ x, float* __restrict__ mu) {
  const int b   = blockIdx.x >> 6;
  const int c0  = (blockIdx.x & 63) << 4;
  const int col = threadIdx.x & 15;
  const int rg  = threadIdx.x >> 4;
  const float* p = x + ((size_t)(b * T_ + rg * 128)) * D_ + c0 + col;
  float s = 0.f;
  #pragma unroll 8
  for (int r = 0; r < 128; ++r) s += p[(size_t)r * D_];
  __shared__ float red[16][17];
  red[rg][col] = s;
  __syncthreads();
  if (rg == 0) {
    float t = 0.f;
    #pragma unroll
    for (int i = 0; i < 16; ++i) t += red[i][col];
    mu[b * D_ + c0 + col] = t * (1.f / (float)T_);
  }
}

// ---------------- kernel 2: centered f16, PLANE-MAJOR tiled layouts ---------
// KT [bh][tile 32][plane=d-granule 8][row=key 64][8 f16]  -- scaled by SQL2E
// VT [bh][tile 32][plane=key-granule 8][row=d 64][8 f16]  -- unscaled
__global__ __launch_bounds__(256)
void cvt2_kernel(const float* __restrict__ x, const float* __restrict__ mu,
                 _Float16* __restrict__ KT, _Float16* __restrict__ VT) {
  const int unit = blockIdx.x * 4 + (threadIdx.x >> 6);  // 0..2047
  const int bh   = unit >> 5;
  const int tile = unit & 31;
  const int b    = bh >> 4;
  const int h    = bh & 15;
  const int lane = threadIdx.x & 63;
  const int t    = tile * 64 + lane;

  const float* xr  = x  + ((size_t)(b * T_ + t)) * D_ + h * HD_;
  const float* mur = mu + b * D_ + h * HD_;

  _Float16 cfV[64];   // centered
  _Float16 cfK[64];   // centered * SQL2E (single rounding each)
  #pragma unroll
  for (int u = 0; u < 16; ++u) {
    float4 f = *(const float4*)(xr + u * 4);
    float4 m = *(const float4*)(mur + u * 4);
    float c0 = f.x - m.x, c1 = f.y - m.y, c2 = f.z - m.z, c3 = f.w - m.w;
    cfV[u*4+0] = (_Float16)c0; cfK[u*4+0] = (_Float16)(c0 * SQL2E);
    cfV[u*4+1] = (_Float16)c1; cfK[u*4+1] = (_Float16)(c1 * SQL2E);
    cfV[u*4+2] = (_Float16)c2; cfK[u*4+2] = (_Float16)(c2 * SQL2E);
    cfV[u*4+3] = (_Float16)c3; cfK[u*4+3] = (_Float16)(c3 * SQL2E);
  }
  // K: plane g holds d-granule g of all 64 rows; lane = row -> coalesced 16B
  _Float16* kt = KT + ((size_t)(bh * 32 + tile)) * 4096;
  #pragma unroll
  for (int g = 0; g < 8; ++g)
    *(f16x8*)&kt[g * 512 + lane * 8] = *(const f16x8*)&cfK[g * 8];
  // V: plane = key-granule (lane>>3), row = d, elem-in-granule = lane&7
  _Float16* vt = VT + ((size_t)(bh * 32 + tile)) * 4096 + (lane >> 3) * 512 + (lane & 7);
  #pragma unroll
  for (int d = 0; d < 64; ++d) vt[d * 8] = cfV[d];
}

// ---------------- kernel 3: flash attention, C1VEC-folded softmax -----------
__global__ __launch_bounds__(256, 4)
void attn5_kernel(const _Float16* __restrict__ KT,
                  const _Float16* __restrict__ VT,
                  const float* __restrict__ mu,
                  float* __restrict__ out) {
  __shared__ __align__(16) _Float16 Kb[2][4096];
  __shared__ __align__(16) _Float16 Vb[2][4096];

  const int tid  = threadIdx.x;
  const int lane = tid & 63;
  const int wv   = tid >> 6;
  const int c    = lane & 31;     // column (q) owned by this lane
  const int hp   = lane >> 5;     // lane half

  // XCD swizzle: 16 q-tile blocks of one (b,h) share an XCD
  const int bid = blockIdx.x;
  const int wid = (bid & 7) * 128 + (bid >> 3);
  const int qb  = wid & 15;
  const int bh  = wid >> 4;
  const int b   = bh >> 4;
  const int h   = bh & 15;

  const int q0w = qb * QB + wv * 32;

  // ---- Q B-frags from KT (col=q=c, k=d=16s+8hp+e); KT pre-scaled SQL2E ----
  f16x8 qf[4];
  {
    const _Float16* qt = KT + ((size_t)(bh * 32 + (q0w >> 6))) * 4096;
    const int qrow = ((wv & 1) * 32) + c;
    #pragma unroll
    for (int s = 0; s < 4; ++s)
      qf[s] = *(const f16x8*)&qt[(2 * s + hp) * 512 + qrow * 8];
  }

  // staging sources: wave wv stages K planes {2wv,2wv+1}, V planes {2wv,2wv+1}
  const char* ksrc = (const char*)KT + ((size_t)(bh * 32)) * 8192 + wv * 2048 + lane * 16;
  const char* vsrc = (const char*)VT + ((size_t)(bh * 32)) * 8192 + wv * 2048 + lane * 16;

  const int fb = hp * 512 + c * 8;   // frag base (elems); +s*1024 +kt*256

  f32x16 acc0 = zero16(), acc1 = zero16();
  f32x16 C1 = zero16();              // per-lane: all elements = -m2(column)
  #pragma unroll
  for (int i = 0; i < 16; ++i) C1[i] = -M2INIT;
  float lrun = 0.f;                  // per-lane PARTIAL (half-column) sum
  h16x2 one2; one2[0] = (__fp16)1.0f; one2[1] = (__fp16)1.0f;

  // prologue: stage tile 0
  gld16(ksrc,        &Kb[0][wv * 1024]);
  gld16(ksrc + 1024, &Kb[0][wv * 1024 + 512]);
  gld16(vsrc,        &Vb[0][wv * 1024]);
  gld16(vsrc + 1024, &Vb[0][wv * 1024 + 512]);
  ksrc += 8192; vsrc += 8192;
  __syncthreads();

  int buf = 0;
  for (int step = 0; step < NSTEP; ++step) {
    if (step + 1 < NSTEP) {
      gld16(ksrc,        &Kb[buf ^ 1][wv * 1024]);
      gld16(ksrc + 1024, &Kb[buf ^ 1][wv * 1024 + 512]);
      gld16(vsrc,        &Vb[buf ^ 1][wv * 1024]);
      gld16(vsrc + 1024, &Vb[buf ^ 1][wv * 1024 + 512]);
      ksrc += 8192; vsrc += 8192;
    }
    const _Float16* Kp = &Kb[buf][0];
    const _Float16* Vp = &Vb[buf][0];

    #pragma unroll
    for (int kt = 0; kt < 2; ++kt) {
      // ---- st = K·Q^T·L2E - m2  (C-operand carries -m2 per column) ----
      f32x16 st;
      __builtin_amdgcn_s_setprio(1);
      st = mfma32(*(const f16x8*)&Kp[fb + 0 * 1024 + kt * 256], qf[0], C1);
      st = mfma32(*(const f16x8*)&Kp[fb + 1 * 1024 + kt * 256], qf[1], st);
      st = mfma32(*(const f16x8*)&Kp[fb + 2 * 1024 + kt * 256], qf[2], st);
      st = mfma32(*(const f16x8*)&Kp[fb + 3 * 1024 + kt * 256], qf[3], st);
      __builtin_amdgcn_s_setprio(0);

      // ---- half-column max (max3-fusible tree), overflow guard ----
      float m0 = fmaxf(fmaxf(st[0],  st[1]),  st[2]);
      float m1 = fmaxf(fmaxf(st[3],  st[4]),  st[5]);
      float m2 = fmaxf(fmaxf(st[6],  st[7]),  st[8]);
      float m3 = fmaxf(fmaxf(st[9],  st[10]), st[11]);
      float m4 = fmaxf(fmaxf(st[12], st[13]), st[14]);
      float pm = fmaxf(fmaxf(fmaxf(m0, m1), fmaxf(m2, m3)), fmaxf(m4, st[15]));

      if (!__all(pm <= THR2)) {         // rare: raise m2 for over-guard columns
        const float pmw = fmaxf(pm, __shfl_xor(pm, 32));  // full column max
        const float dm  = fmaxf(pmw, 0.f);
        const float al  = fexp2(-dm);
        lrun *= al;
        #pragma unroll
        for (int i = 0; i < 16; ++i) { C1[i] -= dm; st[i] -= dm; }
        #pragma unroll
        for (int r = 0; r < 16; ++r) {
          const int row = (r & 3) + 8 * (r >> 2) + 4 * hp;
          const float a = __shfl(al, row);
          acc0[r] *= a; acc1[r] *= a;
        }
      }

      // ---- p = exp2(st); pack -> A-frags; partial row-sum via fdot2 ----
      f16x8 paL, paH;
      float rsA = 0.f, rsB = 0.f;
      #pragma unroll
      for (int v = 0; v < 2; ++v) {
        uint32_t A0 = pkrtz_u(fexp2(st[8*v+0]), fexp2(st[8*v+1]));
        uint32_t A1 = pkrtz_u(fexp2(st[8*v+2]), fexp2(st[8*v+3]));
        uint32_t B0 = pkrtz_u(fexp2(st[8*v+4]), fexp2(st[8*v+5]));
        uint32_t B1 = pkrtz_u(fexp2(st[8*v+6]), fexp2(st[8*v+7]));
        rsA = fdot2_u(A0, one2, rsA); rsA = fdot2_u(A1, one2, rsA);
        rsB = fdot2_u(B0, one2, rsB); rsB = fdot2_u(B1, one2, rsB);
        pl32swap(A0, B0);
        pl32swap(A1, B1);
        if (v == 0) paL = mk_frag(A0, A1, B0, B1);
        else        paH = mk_frag(A0, A1, B0, B1);
      }
      lrun += rsA + rsB;                // per-lane partial; combined at end

      // ---- O += P-slice · V (slices s'=2kt, 2kt+1) ----
      __builtin_amdgcn_s_setprio(1);
      acc0 = mfma32(paL, *(const f16x8*)&Vp[fb + (2*kt    ) * 1024      ], acc0);
      acc0 = mfma32(paH, *(const f16x8*)&Vp[fb + (2*kt + 1) * 1024      ], acc0);
      acc1 = mfma32(paL, *(const f16x8*)&Vp[fb + (2*kt    ) * 1024 + 256], acc1);
      acc1 = mfma32(paH, *(const f16x8*)&Vp[fb + (2*kt + 1) * 1024 + 256], acc1);
      __builtin_amdgcn_s_setprio(0);
    }

    __syncthreads();   // drains gld16 (vmcnt0) + all waves' LDS reads
    buf ^= 1;
  }

  // ---- epilogue: combine half-column sums; out = acc / l + mu ----
  const float ltot = lrun + __shfl_xor(lrun, 32);
  const float linv = 1.0f / ltot;
  const float mv0 = mu[b * D_ + h * HD_ + c];
  const float mv1 = mu[b * D_ + h * HD_ + 32 + c];
  #pragma unroll
  for (int r = 0; r < 16; ++r) {
    const int row = (r & 3) + 8 * (r >> 2) + 4 * hp;
    const float lr = __shfl(linv, row);
    const int q = q0w + row;
    float* orow = out + (size_t)(b * T_ + q) * D_ + h * HD_;
    orow[c]      = acc0[r] * lr + mv0;
    orow[32 + c] = acc1[r] * lr + mv1;
  }
}

// ---------------- fallback: verified round-1 kernel (small ws) --------------
__global__ __launch_bounds__(256)
void attn_fb_kernel(const float* __restrict__ x, const float* __restrict__ mu,
                    float* __restrict__ out) {
  __shared__ __align__(16) _Float16 Kt[64 * 64];
  __shared__ __align__(16) _Float16 Vt[64 * 64];
  __shared__ __align__(16) _Float16 Pl[4][2][16 * 64];

  const int tid  = threadIdx.x;
  const int lane = tid & 63;
  const int wv   = tid >> 6;
  const int j    = lane & 15;
  const int g    = lane >> 4;

  const int qb = blockIdx.x & 15;
  const int bh = blockIdx.x >> 4;
  const int b  = bh >> 4;
  const int h  = bh & 15;

  const float* xb  = x  + (size_t)b * T_ * D_;
  const float* muh = mu + b * D_ + h * HD_;

  f16x8 qf[2][2];
  const int q0 = qb * QB + wv * 32;
  #pragma unroll
  for (int qt = 0; qt < 2; ++qt) {
    const float* qrow = xb + (size_t)(q0 + qt * 16 + j) * D_ + h * HD_;
    #pragma unroll
    for (int ks = 0; ks < 2; ++ks) {
      const int d0 = ks * 32 + g * 8;
      float4 a  = *(const float4*)(qrow + d0);
      float4 cc = *(const float4*)(qrow + d0 + 4);
      float4 m0 = *(const float4*)(muh + d0);
      float4 m1 = *(const float4*)(muh + d0 + 4);
      f16x8 f;
      f[0] = (_Float16)(a.x - m0.x); f[1] = (_Float16)(a.y - m0.y);
      f[2] = (_Float16)(a.z - m0.z); f[3] = (_Float16)(a.w - m0.w);
      f[4] = (_Float16)(cc.x - m1.x); f[5] = (_Float16)(cc.y - m1.y);
      f[6] = (_Float16)(cc.z - m1.z); f[7] = (_Float16)(cc.w - m1.w);
      qf[qt][ks] = f;
    }
  }

  const int kd0 = (tid & 7) * 8;
  const float4 kmu0 = *(const float4*)(muh + kd0);
  const float4 kmu1 = *(const float4*)(muh + kd0 + 4);
  const int vd2 = (tid & 31) * 2;
  const int vkc = tid >> 5;

  f32x4 acc[2][4];
  float mrun[2][4], lrun[2][4];
  #pragma unroll
  for (int qt = 0; qt < 2; ++qt) {
    #pragma unroll
    for (int n = 0; n < 4; ++n) acc[qt][n] = f32x4{0.f, 0.f, 0.f, 0.f};
    #pragma unroll
    for (int r = 0; r < 4; ++r) { mrun[qt][r] = -1e30f; lrun[qt][r] = 0.f; }
  }

  const int swj = (j & 7) << 3;

  for (int step = 0; step < NSTEP; ++step) {
    const size_t krow0 = (size_t)(step * KB) * D_ + h * HD_;
    __syncthreads();

    #pragma unroll
    for (int cc2 = 0; cc2 < 2; ++cc2) {
      const int kk = (tid >> 3) + cc2 * 32;
      const float* src = xb + krow0 + (size_t)kk * D_ + kd0;
      float4 a = *(const float4*)src;
      float4 cc = *(const float4*)(src + 4);
      f16x8 f;
      f[0] = (_Float16)(a.x - kmu0.x); f[1] = (_Float16)(a.y - kmu0.y);
      f[2] = (_Float16)(a.z - kmu0.z); f[3] = (_Float16)(a.w - kmu0.w);
      f[4] = (_Float16)(cc.x - kmu1.x); f[5] = (_Float16)(cc.y - kmu1.y);
      f[6] = (_Float16)(cc.z - kmu1.z); f[7] = (_Float16)(cc.w - kmu1.w);
      *(f16x8*)&Kt[kk * 64 + (kd0 ^ ((kk & 7) << 3))] = f;
    }
    {
      float2 t[8];
      #pragma unroll
      for (int e = 0; e < 8; ++e)
        t[e] = *(const float2*)(xb + krow0 + (size_t)(vkc * 8 + e) * D_ + vd2);
      f16x8 f0, f1;
      #pragma unroll
      for (int e = 0; e < 8; ++e) { f0[e] = (_Float16)t[e].x; f1[e] = (_Float16)t[e].y; }
      *(f16x8*)&Vt[(vd2    ) * 64 + ((vkc * 8) ^ (((vd2    ) & 7) << 3))] = f0;
      *(f16x8*)&Vt[(vd2 + 1) * 64 + ((vkc * 8) ^ (((vd2 + 1) & 7) << 3))] = f1;
    }
    __syncthreads();

    f32x4 s[2][4];
    #pragma unroll
    for (int n = 0; n < 4; ++n) {
      const int rb = (n * 16 + j) * 64;
      f16x8 kb0 = *(const f16x8*)&Kt[rb + (((     g * 8)) ^ swj)];
      f16x8 kb1 = *(const f16x8*)&Kt[rb + (((32 + g * 8)) ^ swj)];
      #pragma unroll
      for (int qt = 0; qt < 2; ++qt) {
        f32x4 z = f32x4{0.f, 0.f, 0.f, 0.f};
        z = mfma16(qf[qt][0], kb0, z);
        s[qt][n] = mfma16(qf[qt][1], kb1, z);
      }
    }

    #pragma unroll
    for (int qt = 0; qt < 2; ++qt) {
      float al[4];
      #pragma unroll
      for (int r = 0; r < 4; ++r) {
        float v = fmaxf(fmaxf(s[qt][0][r], s[qt][1][r]),
                        fmaxf(s[qt][2][r], s[qt][3][r]));
        v = fmaxf(v, __shfl_xor(v, 1, 16));
        v = fmaxf(v, __shfl_xor(v, 2, 16));
        v = fmaxf(v, __shfl_xor(v, 4, 16));
        v = fmaxf(v, __shfl_xor(v, 8, 16));
        const float mn = fmaxf(mrun[qt][r], v);
        al[r] = exp2f((mrun[qt][r] - mn) * L2E);
        mrun[qt][r] = mn;
        float p0 = exp2f((s[qt][0][r] - mn) * L2E);
        float p1 = exp2f((s[qt][1][r] - mn) * L2E);
        float p2 = exp2f((s[qt][2][r] - mn) * L2E);
        float p3 = exp2f((s[qt][3][r] - mn) * L2E);
        float rs = (p0 + p1) + (p2 + p3);
        rs += __shfl_xor(rs, 1, 16);
        rs += __shfl_xor(rs, 2, 16);
        rs += __shfl_xor(rs, 4, 16);
        rs += __shfl_xor(rs, 8, 16);
        lrun[qt][r] = lrun[qt][r] * al[r] + rs;
        const int q   = g * 4 + r;
        const int qsw = (q & 7) << 3;
        _Float16* prow = &Pl[wv][qt][q * 64];
        prow[(     j) ^ qsw] = (_Float16)p0;
        prow[(16 + j) ^ qsw] = (_Float16)p1;
        prow[(32 + j) ^ qsw] = (_Float16)p2;
        prow[(48 + j) ^ qsw] = (_Float16)p3;
      }
      #pragma unroll
      for (int n = 0; n < 4; ++n) {
        acc[qt][n][0] *= al[0]; acc[qt][n][1] *= al[1];
        acc[qt][n][2] *= al[2]; acc[qt][n][3] *= al[3];
      }
    }

    asm volatile("s_waitcnt lgkmcnt(0)" ::: "memory");

    f16x8 pa[2][2];
    #pragma unroll
    for (int qt = 0; qt < 2; ++qt) {
      const _Float16* Pw = &Pl[wv][qt][0];
      pa[qt][0] = *(const f16x8*)&Pw[j * 64 + (((     g * 8)) ^ swj)];
      pa[qt][1] = *(const f16x8*)&Pw[j * 64 + (((32 + g * 8)) ^ swj)];
    }
    #pragma unroll
    for (int n = 0; n < 4; ++n) {
      const int rb = (n * 16 + j) * 64;
      f16x8 v0 = *(const f16x8*)&Vt[rb + (((     g * 8)) ^ swj)];
      f16x8 v1 = *(const f16x8*)&Vt[rb + (((32 + g * 8)) ^ swj)];
      #pragma unroll
      for (int qt = 0; qt < 2; ++qt) {
        acc[qt][n] = mfma16(pa[qt][0], v0, acc[qt][n]);
        acc[qt][n] = mfma16(pa[qt][1], v1, acc[qt][n]);
      }
    }
  }

  #pragma unroll
  for (int qt = 0; qt < 2; ++qt) {
    float inv[4];
    #pragma unroll
    for (int r = 0; r < 4; ++r) inv[r] = 1.0f / lrun[qt][r];
    #pragma unroll
    for (int n = 0; n < 4; ++n) {
      #pragma unroll
      for (int r = 0; r < 4; ++r) {
        const int q = q0 + qt * 16 + g * 4 + r;
        out[(size_t)(b * T_ + q) * D_ + h * HD_ + n * 16 + j] =
            acc[qt][n][r] * inv[r];
      }
    }
  }
}

extern "C" void kernel_launch(void* const* d_in, const int* in_sizes, int n_in,
                              void* d_out, int out_size, void* d_ws, size_t ws_size,
                              hipStream_t stream) {
  (void)in_sizes; (void)n_in; (void)out_size;
  const float* x  = (const float*)d_in[0];
  float* outp     = (float*)d_out;

  const size_t MU_BYTES  = (size_t)B_ * D_ * sizeof(float);     // 16 KB
  const size_t C16_BYTES = (size_t)B_ * T_ * D_ * 2;            // 16 MB

  float* mu = (float*)d_ws;
  hipLaunchKernelGGL(colmean_kernel, dim3(B_ * 64), dim3(256), 0, stream, x, mu);

  if (ws_size >= MU_BYTES + 2 * C16_BYTES) {
    _Float16* KT = (_Float16*)((char*)d_ws + MU_BYTES);
    _Float16* VT = (_Float16*)((char*)d_ws + MU_BYTES + C16_BYTES);
    hipLaunchKernelGGL(cvt2_kernel, dim3(512), dim3(256), 0, stream, x, mu, KT, VT);
    hipLaunchKernelGGL(attn5_kernel, dim3((T_ / QB) * B_ * H_), dim3(256), 0, stream,
                       KT, VT, mu, outp);
  } else {
    hipLaunchKernelGGL(attn_fb_kernel, dim3((T_ / QB) * B_ * H_), dim3(256), 0, stream,
                       x, mu, outp);
  }
}

// Round 7
// 112.043 us; speedup vs baseline: 3.5917x; 1.0110x over previous
//
#include <hip/hip_runtime.h>
#include <stdint.h>

// x: [B=4][T=2048][D=1024] fp32, H=16 heads, hd=64.
#define B_   4
#define T_   2048
#define H_   16
#define HD_  64
#define D_   1024
#define QB   128              // query rows per block (4 waves x 32)
#define KB   64               // key rows per KV step
#define NSTEP (T_ / KB)       // 32
#define L2E   1.44269504088896f
#define SQL2E 1.20112240878645f   // sqrt(log2 e)
#define THR2  15.5f           // exp2-space guard: p <= 2^15.5 < f16 max
#define M2INIT 28.8539f       // 20 * L2E

typedef __attribute__((ext_vector_type(4)))  float    f32x4;
typedef __attribute__((ext_vector_type(16))) float    f32x16;
typedef __attribute__((ext_vector_type(8)))  _Float16 f16x8;
typedef __attribute__((ext_vector_type(2)))  __fp16   h16x2;   // builtin-native f16x2

__device__ __forceinline__ f32x4 mfma16(f16x8 a, f16x8 b, f32x4 c) {
  return __builtin_amdgcn_mfma_f32_16x16x32_f16(a, b, c, 0, 0, 0);
}
__device__ __forceinline__ f32x16 mfma32(f16x8 a, f16x8 b, f32x16 c) {
  return __builtin_amdgcn_mfma_f32_32x32x16_f16(a, b, c, 0, 0, 0);
}
__device__ __forceinline__ f32x16 zero16() {
  f32x16 z;
  #pragma unroll
  for (int i = 0; i < 16; ++i) z[i] = 0.f;
  return z;
}
__device__ __forceinline__ float fexp2(float x) {
#if __has_builtin(__builtin_amdgcn_exp2f)
  return __builtin_amdgcn_exp2f(x);
#else
  return exp2f(x);
#endif
}
__device__ __forceinline__ uint32_t pkrtz_u(float a, float b) {
  h16x2 r = __builtin_amdgcn_cvt_pkrtz(a, b);
  return __builtin_bit_cast(uint32_t, r);
}
__device__ __forceinline__ float fdot2_u(uint32_t a, h16x2 ones, float c) {
  return __builtin_amdgcn_fdot2(__builtin_bit_cast(h16x2, a), ones, c, false);
}
// v_permlane32_swap_b32 d, s: d's upper 32 lanes <-> s's lower 32 lanes.
__device__ __forceinline__ void pl32swap(uint32_t& a, uint32_t& b) {
  asm volatile("v_permlane32_swap_b32 %0, %1" : "+v"(a), "+v"(b));
}
__device__ __forceinline__ f16x8 mk_frag(uint32_t u0, uint32_t u1,
                                         uint32_t u2, uint32_t u3) {
  union { uint32_t u[4]; f16x8 v; } x;
  x.u[0] = u0; x.u[1] = u1; x.u[2] = u2; x.u[3] = u3;
  return x.v;
}
// async global->LDS, 16B/lane; LDS dest = wave-uniform base + lane*16
__device__ __forceinline__ void gld16(const void* g, void* l) {
  __builtin_amdgcn_global_load_lds(
      (const __attribute__((address_space(1))) uint32_t*)g,
      (__attribute__((address_space(3))) uint32_t*)l, 16, 0, 0);
}

// ---------------- kernel 1: per-(b,d) column mean over T --------------------
__global__ __launch_bounds__(256)
void colmean_kernel(const float* __restrict__ x, float* __restrict__ mu) {
  const int b   = blockIdx.x >> 6;
  const int c0  = (blockIdx.x & 63) << 4;
  const int col = threadIdx.x & 15;
  const int rg  = threadIdx.x >> 4;
  const float* p = x + ((size_t)(b * T_ + rg * 128)) * D_ + c0 + col;
  float s = 0.f;
  #pragma unroll 8
  for (int r = 0; r < 128; ++r) s += p[(size_t)r * D_];
  __shared__ float red[16][17];
  red[rg][col] = s;
  __syncthreads();
  if (rg == 0) {
    float t = 0.f;
    #pragma unroll
    for (int i = 0; i < 16; ++i) t += red[i][col];
    mu[b * D_ + c0 + col] = t * (1.f / (float)T_);
  }
}

// ---------------- kernel 2: centered f16, PLANE-MAJOR tiled layouts ---------
// KT [bh][tile 32][plane=d-granule 8][row=key 64][8 f16]  -- scaled by SQL2E
// VT [bh][tile 32][plane=key-granule 8][row=d 64][8 f16]  -- unscaled
__global__ __launch_bounds__(256)
void cvt2_kernel(const float* __restrict__ x, const float* __restrict__ mu,
                 _Float16* __restrict__ KT, _Float16* __restrict__ VT) {
  const int unit = blockIdx.x * 4 + (threadIdx.x >> 6);  // 0..2047
  const int bh   = unit >> 5;
  const int tile = unit & 31;
  const int b    = bh >> 4;
  const int h    = bh & 15;
  const int lane = threadIdx.x & 63;
  const int t    = tile * 64 + lane;

  const float* xr  = x  + ((size_t)(b * T_ + t)) * D_ + h * HD_;
  const float* mur = mu + b * D_ + h * HD_;

  _Float16 cfV[64];   // centered
  _Float16 cfK[64];   // centered * SQL2E (single rounding each)
  #pragma unroll
  for (int u = 0; u < 16; ++u) {
    float4 f = *(const float4*)(xr + u * 4);
    float4 m = *(const float4*)(mur + u * 4);
    float c0 = f.x - m.x, c1 = f.y - m.y, c2 = f.z - m.z, c3 = f.w - m.w;
    cfV[u*4+0] = (_Float16)c0; cfK[u*4+0] = (_Float16)(c0 * SQL2E);
    cfV[u*4+1] = (_Float16)c1; cfK[u*4+1] = (_Float16)(c1 * SQL2E);
    cfV[u*4+2] = (_Float16)c2; cfK[u*4+2] = (_Float16)(c2 * SQL2E);
    cfV[u*4+3] = (_Float16)c3; cfK[u*4+3] = (_Float16)(c3 * SQL2E);
  }
  // K: plane g holds d-granule g of all 64 rows; lane = row -> coalesced 16B
  _Float16* kt = KT + ((size_t)(bh * 32 + tile)) * 4096;
  #pragma unroll
  for (int g = 0; g < 8; ++g)
    *(f16x8*)&kt[g * 512 + lane * 8] = *(const f16x8*)&cfK[g * 8];
  // V: plane = key-granule (lane>>3), row = d, elem-in-granule = lane&7
  _Float16* vt = VT + ((size_t)(bh * 32 + tile)) * 4096 + (lane >> 3) * 512 + (lane & 7);
  #pragma unroll
  for (int d = 0; d < 64; ++d) vt[d * 8] = cfV[d];
}

// ---------------- kernel 3: flash attention, K-in-LDS, V-from-L2 ------------
__global__ __launch_bounds__(256, 4)
void attn6_kernel(const _Float16* __restrict__ KT,
                  const _Float16* __restrict__ VT,
                  const float* __restrict__ mu,
                  float* __restrict__ out) {
  __shared__ __align__(16) _Float16 Kb[2][4096];   // K only; V comes from L2

  const int tid  = threadIdx.x;
  const int lane = tid & 63;
  const int wv   = tid >> 6;
  const int c    = lane & 31;     // column (q) owned by this lane
  const int hp   = lane >> 5;     // lane half

  // XCD swizzle: 16 q-tile blocks of one (b,h) share an XCD
  const int bid = blockIdx.x;
  const int wid = (bid & 7) * 128 + (bid >> 3);
  const int qb  = wid & 15;
  const int bh  = wid >> 4;
  const int b   = bh >> 4;
  const int h   = bh & 15;

  const int q0w = qb * QB + wv * 32;

  // ---- Q B-frags from KT (col=q=c, k=d=16s+8hp+e); KT pre-scaled SQL2E ----
  f16x8 qf[4];
  {
    const _Float16* qt = KT + ((size_t)(bh * 32 + (q0w >> 6))) * 4096;
    const int qrow = ((wv & 1) * 32) + c;
    #pragma unroll
    for (int s = 0; s < 4; ++s)
      qf[s] = *(const f16x8*)&qt[(2 * s + hp) * 512 + qrow * 8];
  }

  // K staging source: wave wv stages planes {2wv, 2wv+1}
  const char* ksrc = (const char*)KT + ((size_t)(bh * 32)) * 8192 + wv * 2048 + lane * 16;
  const int fb = hp * 512 + c * 8;   // frag base (elems); +s*1024 +kt*256

  // V fragment source (global, L2-resident): per-step tile + frag base
  const _Float16* vfrag = VT + ((size_t)(bh * 32)) * 4096 + fb;

  f32x16 acc0 = zero16(), acc1 = zero16();
  f32x16 C1 = zero16();              // per-lane: all elements = -m2
  #pragma unroll
  for (int i = 0; i < 16; ++i) C1[i] = -M2INIT;
  float lrun = 0.f;                  // per-lane PARTIAL (half-column) sum
  h16x2 one2; one2[0] = (__fp16)1.0f; one2[1] = (__fp16)1.0f;

  // prologue: stage K tile 0
  gld16(ksrc,        &Kb[0][wv * 1024]);
  gld16(ksrc + 1024, &Kb[0][wv * 1024 + 512]);
  ksrc += 8192;
  __syncthreads();

  #pragma unroll 2
  for (int step = 0; step < NSTEP; ++step) {
    const int buf = step & 1;
    if (step + 1 < NSTEP) {
      gld16(ksrc,        &Kb[buf ^ 1][wv * 1024]);
      gld16(ksrc + 1024, &Kb[buf ^ 1][wv * 1024 + 512]);
      ksrc += 8192;
    }
    const _Float16* Kp = &Kb[buf][0];
    const _Float16* Vp = vfrag + (size_t)step * 4096;

    #pragma unroll
    for (int kt = 0; kt < 2; ++kt) {
      // ---- issue V loads early (L2 hit ~200cy, covered by QK+softmax) ----
      f16x8 v0a = *(const f16x8*)&Vp[(2*kt    ) * 1024      ];
      f16x8 v1a = *(const f16x8*)&Vp[(2*kt + 1) * 1024      ];
      f16x8 v0b = *(const f16x8*)&Vp[(2*kt    ) * 1024 + 256];
      f16x8 v1b = *(const f16x8*)&Vp[(2*kt + 1) * 1024 + 256];

      // ---- st = K·Q^T·L2E - m2  (C-operand carries -m2 per column) ----
      f32x16 st;
      __builtin_amdgcn_s_setprio(1);
      st = mfma32(*(const f16x8*)&Kp[fb + 0 * 1024 + kt * 256], qf[0], C1);
      st = mfma32(*(const f16x8*)&Kp[fb + 1 * 1024 + kt * 256], qf[1], st);
      st = mfma32(*(const f16x8*)&Kp[fb + 2 * 1024 + kt * 256], qf[2], st);
      st = mfma32(*(const f16x8*)&Kp[fb + 3 * 1024 + kt * 256], qf[3], st);
      __builtin_amdgcn_s_setprio(0);

      // ---- half-column max (max3-fusible tree), overflow guard ----
      float m0 = fmaxf(fmaxf(st[0],  st[1]),  st[2]);
      float m1 = fmaxf(fmaxf(st[3],  st[4]),  st[5]);
      float m2 = fmaxf(fmaxf(st[6],  st[7]),  st[8]);
      float m3 = fmaxf(fmaxf(st[9],  st[10]), st[11]);
      float m4 = fmaxf(fmaxf(st[12], st[13]), st[14]);
      float pm = fmaxf(fmaxf(fmaxf(m0, m1), fmaxf(m2, m3)), fmaxf(m4, st[15]));

      if (!__all(pm <= THR2)) {         // rare: raise m2 for over-guard columns
        const float pmw = fmaxf(pm, __shfl_xor(pm, 32));  // full column max
        const float dm  = fmaxf(pmw, 0.f);
        const float al  = fexp2(-dm);
        lrun *= al;
        #pragma unroll
        for (int i = 0; i < 16; ++i) { C1[i] -= dm; st[i] -= dm; }
        #pragma unroll
        for (int r = 0; r < 16; ++r) {
          const int row = (r & 3) + 8 * (r >> 2) + 4 * hp;
          const float a = __shfl(al, row);
          acc0[r] *= a; acc1[r] *= a;
        }
      }

      // ---- p = exp2(st); pack -> A-frags; partial row-sum via fdot2 ----
      f16x8 paL, paH;
      float rsA = 0.f, rsB = 0.f;
      #pragma unroll
      for (int v = 0; v < 2; ++v) {
        uint32_t A0 = pkrtz_u(fexp2(st[8*v+0]), fexp2(st[8*v+1]));
        uint32_t A1 = pkrtz_u(fexp2(st[8*v+2]), fexp2(st[8*v+3]));
        uint32_t B0 = pkrtz_u(fexp2(st[8*v+4]), fexp2(st[8*v+5]));
        uint32_t B1 = pkrtz_u(fexp2(st[8*v+6]), fexp2(st[8*v+7]));
        rsA = fdot2_u(A0, one2, rsA); rsA = fdot2_u(A1, one2, rsA);
        rsB = fdot2_u(B0, one2, rsB); rsB = fdot2_u(B1, one2, rsB);
        pl32swap(A0, B0);
        pl32swap(A1, B1);
        if (v == 0) paL = mk_frag(A0, A1, B0, B1);
        else        paH = mk_frag(A0, A1, B0, B1);
      }
      lrun += rsA + rsB;                // per-lane partial; combined at end

      // ---- O += P-slice · V ----
      __builtin_amdgcn_s_setprio(1);
      acc0 = mfma32(paL, v0a, acc0);
      acc0 = mfma32(paH, v1a, acc0);
      acc1 = mfma32(paL, v0b, acc1);
      acc1 = mfma32(paH, v1b, acc1);
      __builtin_amdgcn_s_setprio(0);
    }

    __syncthreads();   // drains gld16 (vmcnt0) + all waves' K reads
  }

  // ---- epilogue: combine half-column sums; out = acc / l + mu ----
  const float ltot = lrun + __shfl_xor(lrun, 32);
  const float linv = 1.0f / ltot;
  const float mv0 = mu[b * D_ + h * HD_ + c];
  const float mv1 = mu[b * D_ + h * HD_ + 32 + c];
  #pragma unroll
  for (int r = 0; r < 16; ++r) {
    const int row = (r & 3) + 8 * (r >> 2) + 4 * hp;
    const float lr = __shfl(linv, row);
    const int q = q0w + row;
    float* orow = out + (size_t)(b * T_ + q) * D_ + h * HD_;
    orow[c]      = acc0[r] * lr + mv0;
    orow[32 + c] = acc1[r] * lr + mv1;
  }
}

// ---------------- fallback: verified round-1 kernel (small ws) --------------
__global__ __launch_bounds__(256)
void attn_fb_kernel(const float* __restrict__ x, const float* __restrict__ mu,
                    float* __restrict__ out) {
  __shared__ __align__(16) _Float16 Kt[64 * 64];
  __shared__ __align__(16) _Float16 Vt[64 * 64];
  __shared__ __align__(16) _Float16 Pl[4][2][16 * 64];

  const int tid  = threadIdx.x;
  const int lane = tid & 63;
  const int wv   = tid >> 6;
  const int j    = lane & 15;
  const int g    = lane >> 4;

  const int qb = blockIdx.x & 15;
  const int bh = blockIdx.x >> 4;
  const int b  = bh >> 4;
  const int h  = bh & 15;

  const float* xb  = x  + (size_t)b * T_ * D_;
  const float* muh = mu + b * D_ + h * HD_;

  f16x8 qf[2][2];
  const int q0 = qb * QB + wv * 32;
  #pragma unroll
  for (int qt = 0; qt < 2; ++qt) {
    const float* qrow = xb + (size_t)(q0 + qt * 16 + j) * D_ + h * HD_;
    #pragma unroll
    for (int ks = 0; ks < 2; ++ks) {
      const int d0 = ks * 32 + g * 8;
      float4 a  = *(const float4*)(qrow + d0);
      float4 cc = *(const float4*)(qrow + d0 + 4);
      float4 m0 = *(const float4*)(muh + d0);
      float4 m1 = *(const float4*)(muh + d0 + 4);
      f16x8 f;
      f[0] = (_Float16)(a.x - m0.x); f[1] = (_Float16)(a.y - m0.y);
      f[2] = (_Float16)(a.z - m0.z); f[3] = (_Float16)(a.w - m0.w);
      f[4] = (_Float16)(cc.x - m1.x); f[5] = (_Float16)(cc.y - m1.y);
      f[6] = (_Float16)(cc.z - m1.z); f[7] = (_Float16)(cc.w - m1.w);
      qf[qt][ks] = f;
    }
  }

  const int kd0 = (tid & 7) * 8;
  const float4 kmu0 = *(const float4*)(muh + kd0);
  const float4 kmu1 = *(const float4*)(muh + kd0 + 4);
  const int vd2 = (tid & 31) * 2;
  const int vkc = tid >> 5;

  f32x4 acc[2][4];
  float mrun[2][4], lrun[2][4];
  #pragma unroll
  for (int qt = 0; qt < 2; ++qt) {
    #pragma unroll
    for (int n = 0; n < 4; ++n) acc[qt][n] = f32x4{0.f, 0.f, 0.f, 0.f};
    #pragma unroll
    for (int r = 0; r < 4; ++r) { mrun[qt][r] = -1e30f; lrun[qt][r] = 0.f; }
  }

  const int swj = (j & 7) << 3;

  for (int step = 0; step < NSTEP; ++step) {
    const size_t krow0 = (size_t)(step * KB) * D_ + h * HD_;
    __syncthreads();

    #pragma unroll
    for (int cc2 = 0; cc2 < 2; ++cc2) {
      const int kk = (tid >> 3) + cc2 * 32;
      const float* src = xb + krow0 + (size_t)kk * D_ + kd0;
      float4 a = *(const float4*)src;
      float4 cc = *(const float4*)(src + 4);
      f16x8 f;
      f[0] = (_Float16)(a.x - kmu0.x); f[1] = (_Float16)(a.y - kmu0.y);
      f[2] = (_Float16)(a.z - kmu0.z); f[3] = (_Float16)(a.w - kmu0.w);
      f[4] = (_Float16)(cc.x - kmu1.x); f[5] = (_Float16)(cc.y - kmu1.y);
      f[6] = (_Float16)(cc.z - kmu1.z); f[7] = (_Float16)(cc.w - kmu1.w);
      *(f16x8*)&Kt[kk * 64 + (kd0 ^ ((kk & 7) << 3))] = f;
    }
    {
      float2 t[8];
      #pragma unroll
      for (int e = 0; e < 8; ++e)
        t[e] = *(const float2*)(xb + krow0 + (size_t)(vkc * 8 + e) * D_ + vd2);
      f16x8 f0, f1;
      #pragma unroll
      for (int e = 0; e < 8; ++e) { f0[e] = (_Float16)t[e].x; f1[e] = (_Float16)t[e].y; }
      *(f16x8*)&Vt[(vd2    ) * 64 + ((vkc * 8) ^ (((vd2    ) & 7) << 3))] = f0;
      *(f16x8*)&Vt[(vd2 + 1) * 64 + ((vkc * 8) ^ (((vd2 + 1) & 7) << 3))] = f1;
    }
    __syncthreads();

    f32x4 s[2][4];
    #pragma unroll
    for (int n = 0; n < 4; ++n) {
      const int rb = (n * 16 + j) * 64;
      f16x8 kb0 = *(const f16x8*)&Kt[rb + (((     g * 8)) ^ swj)];
      f16x8 kb1 = *(const f16x8*)&Kt[rb + (((32 + g * 8)) ^ swj)];
      #pragma unroll
      for (int qt = 0; qt < 2; ++qt) {
        f32x4 z = f32x4{0.f, 0.f, 0.f, 0.f};
        z = mfma16(qf[qt][0], kb0, z);
        s[qt][n] = mfma16(qf[qt][1], kb1, z);
      }
    }

    #pragma unroll
    for (int qt = 0; qt < 2; ++qt) {
      float al[4];
      #pragma unroll
      for (int r = 0; r < 4; ++r) {
        float v = fmaxf(fmaxf(s[qt][0][r], s[qt][1][r]),
                        fmaxf(s[qt][2][r], s[qt][3][r]));
        v = fmaxf(v, __shfl_xor(v, 1, 16));
        v = fmaxf(v, __shfl_xor(v, 2, 16));
        v = fmaxf(v, __shfl_xor(v, 4, 16));
        v = fmaxf(v, __shfl_xor(v, 8, 16));
        const float mn = fmaxf(mrun[qt][r], v);
        al[r] = exp2f((mrun[qt][r] - mn) * L2E);
        mrun[qt][r] = mn;
        float p0 = exp2f((s[qt][0][r] - mn) * L2E);
        float p1 = exp2f((s[qt][1][r] - mn) * L2E);
        float p2 = exp2f((s[qt][2][r] - mn) * L2E);
        float p3 = exp2f((s[qt][3][r] - mn) * L2E);
        float rs = (p0 + p1) + (p2 + p3);
        rs += __shfl_xor(rs, 1, 16);
        rs += __shfl_xor(rs, 2, 16);
        rs += __shfl_xor(rs, 4, 16);
        rs += __shfl_xor(rs, 8, 16);
        lrun[qt][r] = lrun[qt][r] * al[r] + rs;
        const int q   = g * 4 + r;
        const int qsw = (q & 7) << 3;
        _Float16* prow = &Pl[wv][qt][q * 64];
        prow[(     j) ^ qsw] = (_Float16)p0;
        prow[(16 + j) ^ qsw] = (_Float16)p1;
        prow[(32 + j) ^ qsw] = (_Float16)p2;
        prow[(48 + j) ^ qsw] = (_Float16)p3;
      }
      #pragma unroll
      for (int n = 0; n < 4; ++n) {
        acc[qt][n][0] *= al[0]; acc[qt][n][1] *= al[1];
        acc[qt][n][2] *= al[2]; acc[qt][n][3] *= al[3];
      }
    }

    asm volatile("s_waitcnt lgkmcnt(0)" ::: "memory");

    f16x8 pa[2][2];
    #pragma unroll
    for (int qt = 0; qt < 2; ++qt) {
      const _Float16* Pw = &Pl[wv][qt][0];
      pa[qt][0] = *(const f16x8*)&Pw[j * 64 + (((     g * 8)) ^ swj)];
      pa[qt][1] = *(const f16x8*)&Pw[j * 64 + (((32 + g * 8)) ^ swj)];
    }
    #pragma unroll
    for (int n = 0; n < 4; ++n) {
      const int rb = (n * 16 + j) * 64;
      f16x8 v0 = *(const f16x8*)&Vt[rb + (((     g * 8)) ^ swj)];
      f16x8 v1 = *(const f16x8*)&Vt[rb + (((32 + g * 8)) ^ swj)];
      #pragma unroll
      for (int qt = 0; qt < 2; ++qt) {
        acc[qt][n] = mfma16(pa[qt][0], v0, acc[qt][n]);
        acc[qt][n] = mfma16(pa[qt][1], v1, acc[qt][n]);
      }
    }
  }

  #pragma unroll
  for (int qt = 0; qt < 2; ++qt) {
    float inv[4];
    #pragma unroll
    for (int r = 0; r < 4; ++r) inv[r] = 1.0f / lrun[qt][r];
    #pragma unroll
    for (int n = 0; n < 4; ++n) {
      #pragma unroll
      for (int r = 0; r < 4; ++r) {
        const int q = q0 + qt * 16 + g * 4 + r;
        out[(size_t)(b * T_ + q) * D_ + h * HD_ + n * 16 + j] =
            acc[qt][n][r] * inv[r];
      }
    }
  }
}

extern "C" void kernel_launch(void* const* d_in, const int* in_sizes, int n_in,
                              void* d_out, int out_size, void* d_ws, size_t ws_size,
                              hipStream_t stream) {
  (void)in_sizes; (void)n_in; (void)out_size;
  const float* x  = (const float*)d_in[0];
  float* outp     = (float*)d_out;

  const size_t MU_BYTES  = (size_t)B_ * D_ * sizeof(float);     // 16 KB
  const size_t C16_BYTES = (size_t)B_ * T_ * D_ * 2;            // 16 MB

  float* mu = (float*)d_ws;
  hipLaunchKernelGGL(colmean_kernel, dim3(B_ * 64), dim3(256), 0, stream, x, mu);

  if (ws_size >= MU_BYTES + 2 * C16_BYTES) {
    _Float16* KT = (_Float16*)((char*)d_ws + MU_BYTES);
    _Float16* VT = (_Float16*)((char*)d_ws + MU_BYTES + C16_BYTES);
    hipLaunchKernelGGL(cvt2_kernel, dim3(512), dim3(256), 0, stream, x, mu, KT, VT);
    hipLaunchKernelGGL(attn6_kernel, dim3((T_ / QB) * B_ * H_), dim3(256), 0, stream,
                       KT, VT, mu, outp);
  } else {
    hipLaunchKernelGGL(attn_fb_kernel, dim3((T_ / QB) * B_ * H_), dim3(256), 0, stream,
                       x, mu, outp);
  }
}